// Round 1
// baseline (1243.727 us; speedup 1.0000x reference)
//
#include <hip/hip_runtime.h>
#include <math.h>

// Problem constants: B=2, H=W=32 (after expand), L=1024, out_dim=384, Di=768,
// K=4 directions, N=16 state, R=24, depth=2. All tensors fp32.

static __device__ __forceinline__ float sigmoidf_(float x) {
    return 1.f / (1.f + __expf(-x));
}

// Scan-order <-> spatial-position map. Involution for all k:
// k=0: identity; k=1: (row,col) transpose; k=2: reverse; k=3: reverse∘transpose.
static __device__ __forceinline__ int scan_pos(int k, int l) {
    int m = (k & 2) ? (1023 - l) : l;
    return (k & 1) ? (((m & 31) << 5) | (m >> 5)) : m;
}

// ---------------- transpose x: (B,768,256) NCHW -> (B*256, 768) rows ----------------
__global__ __launch_bounds__(256) void transpose_x_k(const float* __restrict__ x,
                                                     float* __restrict__ o) {
    int m = blockIdx.x;              // 0..511  (b*256 + ij)
    int b = m >> 8, ij = m & 255;
    for (int c = threadIdx.x; c < 768; c += 256)
        o[(size_t)m * 768 + c] = x[((size_t)(b * 768 + c)) * 256 + ij];
}

// ---------------- generic NT GEMM: C[m,n] = sum_k A[m,k]*B[n,k] (+bias[n]) (+res[m,n]) ----
// A: MxK row-major, B: NxK row-major. M%64==0, N%64==0, K%16==0.
__global__ __launch_bounds__(256) void gemm_nt(const float* __restrict__ A,
                                               const float* __restrict__ B,
                                               const float* __restrict__ bias,
                                               const float* __restrict__ res,
                                               float* __restrict__ C,
                                               int M, int N, int K) {
    __shared__ float As[16][68];
    __shared__ float Bs[16][68];
    int tid = threadIdx.x;
    int bm = blockIdx.y * 64, bn = blockIdx.x * 64;
    int tx = tid & 15, ty = tid >> 4;
    int lk = tid & 15, lm = tid >> 4;
    float acc[4][4] = {};
    const float* Ap = A + (size_t)(bm + lm) * K + lk;
    const float* Bp = B + (size_t)(bn + lm) * K + lk;
    for (int k0 = 0; k0 < K; k0 += 16) {
#pragma unroll
        for (int i = 0; i < 4; ++i) {
            As[lk][lm + 16 * i] = Ap[(size_t)(16 * i) * K + k0];
            Bs[lk][lm + 16 * i] = Bp[(size_t)(16 * i) * K + k0];
        }
        __syncthreads();
#pragma unroll
        for (int kk = 0; kk < 16; ++kk) {
            float4 av = *(const float4*)&As[kk][ty * 4];
            float4 bv = *(const float4*)&Bs[kk][tx * 4];
            float a[4] = {av.x, av.y, av.z, av.w};
            float bb[4] = {bv.x, bv.y, bv.z, bv.w};
#pragma unroll
            for (int i = 0; i < 4; ++i)
#pragma unroll
                for (int j = 0; j < 4; ++j) acc[i][j] += a[i] * bb[j];
        }
        __syncthreads();
    }
#pragma unroll
    for (int i = 0; i < 4; ++i) {
        int m = bm + ty * 4 + i;
#pragma unroll
        for (int j = 0; j < 4; ++j) {
            int n = bn + tx * 4 + j;
            float v = acc[i][j];
            if (bias) v += bias[n];
            if (res) v += res[(size_t)m * N + n];
            C[(size_t)m * N + n] = v;
        }
    }
}

// ---------------- pixel-shuffle LN + skip concat: builds cin (2048, 768) ----------------
__global__ __launch_bounds__(256) void pe_concat_k(const float* __restrict__ t1,
                                                   const float* __restrict__ skip,
                                                   const float* __restrict__ pnw,
                                                   const float* __restrict__ pnb,
                                                   float* __restrict__ cin) {
    __shared__ float sh1[256], sh2[256];
    int row = blockIdx.x;           // (b*1024 + p)
    int b = row >> 10, p = row & 1023;
    int r = p >> 5, col = p & 31;
    int i = r >> 1, a = r & 1, j = col >> 1, b2 = col & 1;
    const float* src = t1 + ((size_t)(b * 256 + i * 16 + j)) * 1536 + (a * 2 + b2) * 384;
    int t = threadIdx.x;
    float v0 = src[t];
    float v1 = (t < 128) ? src[t + 256] : 0.f;
    float s1 = v0 + v1, s2 = v0 * v0 + v1 * v1;
    sh1[t] = s1; sh2[t] = s2; __syncthreads();
    for (int s = 128; s > 0; s >>= 1) {
        if (t < s) { sh1[t] += sh1[t + s]; sh2[t] += sh2[t + s]; }
        __syncthreads();
    }
    float mean = sh1[0] * (1.f / 384.f);
    float var = sh2[0] * (1.f / 384.f) - mean * mean;
    float rstd = rsqrtf(var + 1e-5f);
    float* o = cin + (size_t)row * 768;
    o[t] = (v0 - mean) * rstd * pnw[t] + pnb[t];
    if (t < 128) o[t + 256] = (v1 - mean) * rstd * pnw[t + 256] + pnb[t + 256];
    o[384 + t] = skip[((size_t)(b * 384 + t)) * 1024 + p];
    if (t < 128) o[384 + t + 256] = skip[((size_t)(b * 384 + t + 256)) * 1024 + p];
}

// ---------------- row LayerNorm over 384 cols ----------------
__global__ __launch_bounds__(256) void ln_rows_384(const float* __restrict__ in,
                                                   const float* __restrict__ w,
                                                   const float* __restrict__ b,
                                                   float* __restrict__ out) {
    __shared__ float sh1[256], sh2[256];
    int row = blockIdx.x;
    const float* x = in + (size_t)row * 384;
    int t = threadIdx.x;
    float v0 = x[t];
    float v1 = (t < 128) ? x[t + 256] : 0.f;
    float s1 = v0 + v1, s2 = v0 * v0 + v1 * v1;
    sh1[t] = s1; sh2[t] = s2; __syncthreads();
    for (int s = 128; s > 0; s >>= 1) {
        if (t < s) { sh1[t] += sh1[t + s]; sh2[t] += sh2[t + s]; }
        __syncthreads();
    }
    float mean = sh1[0] * (1.f / 384.f);
    float var = sh2[0] * (1.f / 384.f) - mean * mean;
    float rstd = rsqrtf(var + 1e-5f);
    out[(size_t)row * 384 + t] = (v0 - mean) * rstd * w[t] + b[t];
    if (t < 128)
        out[(size_t)row * 384 + t + 256] = (v1 - mean) * rstd * w[t + 256] + b[t + 256];
}

// ---------------- depthwise 3x3 conv (SAME) + bias + SiLU. In: xz cols [0,768) ----------
__global__ __launch_bounds__(256) void conv_silu_k(const float* __restrict__ xz,
                                                   const float* __restrict__ cw,
                                                   const float* __restrict__ cb,
                                                   float* __restrict__ xc) {
    int row = blockIdx.x;
    int b = row >> 10, p = row & 1023;
    int r = p >> 5, col = p & 31;
    for (int d = threadIdx.x; d < 768; d += 256) {
        float acc = cb[d];
#pragma unroll
        for (int dy = 0; dy < 3; ++dy) {
            int rr = r + dy - 1;
            if ((unsigned)rr > 31u) continue;
#pragma unroll
            for (int dx = 0; dx < 3; ++dx) {
                int cc = col + dx - 1;
                if ((unsigned)cc > 31u) continue;
                acc += cw[d * 9 + dy * 3 + dx] *
                       xz[((size_t)(b * 1024 + rr * 32 + cc)) * 1536 + d];
            }
        }
        xc[(size_t)row * 768 + d] = acc * sigmoidf_(acc);
    }
}

// ---------------- x_proj: dbl[b,k,l,0..56) = xp[k] @ xc[pos] , stored in scan order ------
__global__ __launch_bounds__(64) void xproj_k(const float* __restrict__ xc,
                                              const float* __restrict__ xpw,
                                              float* __restrict__ dbl) {
    __shared__ float xs[8][768];
    int k = blockIdx.y;
    int p0 = blockIdx.x * 8;        // global row in [0,2048), 8 rows share b
    const float4* src = (const float4*)(xc + (size_t)p0 * 768);
    float4* dst = (float4*)xs;
    for (int i = threadIdx.x; i < 8 * 768 / 4; i += 64) dst[i] = src[i];
    __syncthreads();
    int c = threadIdx.x;
    if (c >= 56) return;
    const float* w = xpw + ((size_t)(k * 56 + c)) * 768;
    float acc[8] = {};
    for (int q = 0; q < 768; q += 4) {
        float4 wv = *(const float4*)(w + q);
#pragma unroll
        for (int i = 0; i < 8; ++i) {
            float4 xv = *(const float4*)&xs[i][q];
            acc[i] += wv.x * xv.x + wv.y * xv.y + wv.z * xv.z + wv.w * xv.w;
        }
    }
    int b = p0 >> 10;
#pragma unroll
    for (int i = 0; i < 8; ++i) {
        int pp = (p0 + i) & 1023;
        int l = scan_pos(k, pp);    // involution: l(p) == p(l) formula
        dbl[(((size_t)(b * 4 + k)) * 1024 + l) * 56 + c] = acc[i];
    }
}

// ---------------- dt_proj + softplus: dt[b,k,l,d] (scan order) ----------------
__global__ __launch_bounds__(256) void dtproj_k(const float* __restrict__ dbl,
                                                const float* __restrict__ dtw,
                                                const float* __restrict__ dtbias,
                                                float* __restrict__ dt) {
    __shared__ float dr[8][24];
    int row0 = blockIdx.x * 8;      // global over B*K*L = 8192
    int k = (row0 >> 10) & 3;
    for (int i = threadIdx.x; i < 192; i += 256)
        dr[i / 24][i % 24] = dbl[(size_t)(row0 + i / 24) * 56 + (i % 24)];
    __syncthreads();
    int t = threadIdx.x;
#pragma unroll
    for (int j = 0; j < 3; ++j) {
        int d = t + j * 256;
        const float* w = dtw + ((size_t)(k * 768 + d)) * 24;
        float wv[24];
#pragma unroll
        for (int r = 0; r < 24; ++r) wv[r] = w[r];
        float bias = dtbias[k * 768 + d];
#pragma unroll
        for (int i = 0; i < 8; ++i) {
            float acc = bias;
#pragma unroll
            for (int r = 0; r < 24; ++r) acc += wv[r] * dr[i][r];
            float sp = (acc > 20.f) ? acc : log1pf(__expf(acc));
            dt[(size_t)(row0 + i) * 768 + d] = sp;
        }
    }
}

// ---------------- selective scan: 16 lanes (n) per (b,k,d) chain ----------------
// grid (48, 4, 2) = (Di/16, K, B); block 256 = 16 chains.
__global__ __launch_bounds__(256) void scan_k(const float* __restrict__ dt,
                                              const float* __restrict__ dbl,
                                              const float* __restrict__ xc,
                                              const float* __restrict__ alog,
                                              float* __restrict__ y4) {
    int t = threadIdx.x;
    int n = t & 15;
    int chain = t >> 4;
    int d = blockIdx.x * 16 + chain;
    int k = blockIdx.y, b = blockIdx.z;
    // A = -exp(A_log); fold log2(e) so recurrence uses exp2f (v_exp_f32).
    float A2 = -__expf(alog[((size_t)(k * 768 + d)) * 16 + n]) * 1.44269504f;
    const float* dtp = dt + (((size_t)(b * 4 + k)) * 1024) * 768 + d;
    const float* dbp = dbl + (((size_t)(b * 4 + k)) * 1024) * 56;
    const float* xp = xc + (size_t)b * 1024 * 768 + d;
    float* yp = y4 + (((size_t)(b * 4 + k)) * 1024) * 768 + d;
    float h = 0.f;
    int p_c = scan_pos(k, 0);
    float dt_c = dtp[0];
    float u_c = xp[(size_t)p_c * 768];
    float B_c = dbp[24 + n];
    float C_c = dbp[40 + n];
    for (int l = 0; l < 1024; ++l) {
        int p_n = 0; float dt_n = 0.f, u_n = 0.f, B_n = 0.f, C_n = 0.f;
        if (l < 1023) {             // prefetch next step (independent of h chain)
            int ln = l + 1;
            p_n = scan_pos(k, ln);
            dt_n = dtp[(size_t)ln * 768];
            u_n = xp[(size_t)p_n * 768];
            B_n = dbp[ln * 56 + 24 + n];
            C_n = dbp[ln * 56 + 40 + n];
        }
        float a = exp2f(dt_c * A2);
        h = a * h + dt_c * u_c * B_c;
        float part = h * C_c;
        part += __shfl_xor(part, 1);
        part += __shfl_xor(part, 2);
        part += __shfl_xor(part, 4);
        part += __shfl_xor(part, 8);
        if (n == 0) yp[(size_t)p_c * 768] = part;   // write at spatial position
        p_c = p_n; dt_c = dt_n; u_c = u_n; B_c = B_n; C_c = C_n;
    }
}

// ---------------- sum 4 directions + D*u, out-LN, * silu(z) -> g ----------------
__global__ __launch_bounds__(256) void fuse_out_k(const float* __restrict__ y4,
                                                  const float* __restrict__ xc,
                                                  const float* __restrict__ xz,
                                                  const float* __restrict__ ds,
                                                  const float* __restrict__ onw,
                                                  const float* __restrict__ onb,
                                                  float* __restrict__ g) {
    __shared__ float sh1[256], sh2[256];
    int row = blockIdx.x;
    int b = row >> 10, p = row & 1023;
    int t = threadIdx.x;
    float vals[3];
    float s1 = 0.f, s2 = 0.f;
#pragma unroll
    for (int j = 0; j < 3; ++j) {
        int d = t + j * 256;
        float u = xc[(size_t)row * 768 + d];
        float dsum = ds[d] + ds[768 + d] + ds[1536 + d] + ds[2304 + d];
        float v = dsum * u;
#pragma unroll
        for (int k = 0; k < 4; ++k)
            v += y4[(((size_t)(b * 4 + k)) * 1024 + p) * 768 + d];
        vals[j] = v; s1 += v; s2 += v * v;
    }
    sh1[t] = s1; sh2[t] = s2; __syncthreads();
    for (int s = 128; s > 0; s >>= 1) {
        if (t < s) { sh1[t] += sh1[t + s]; sh2[t] += sh2[t + s]; }
        __syncthreads();
    }
    float mean = sh1[0] * (1.f / 768.f);
    float var = sh2[0] * (1.f / 768.f) - mean * mean;
    float rstd = rsqrtf(var + 1e-5f);
#pragma unroll
    for (int j = 0; j < 3; ++j) {
        int d = t + j * 256;
        float zz = xz[(size_t)row * 1536 + 768 + d];
        float sil = zz * sigmoidf_(zz);
        g[(size_t)row * 768 + d] = ((vals[j] - mean) * rstd * onw[d] + onb[d]) * sil;
    }
}

// ---------------- final: (B*L,384) -> (B,384,32,32) ----------------
__global__ __launch_bounds__(256) void out_tr_k(const float* __restrict__ xh,
                                                float* __restrict__ out) {
    int bc = blockIdx.x;            // 0..767 (b*384 + ch)
    int b = bc / 384, ch = bc % 384;
    for (int p = threadIdx.x; p < 1024; p += 256)
        out[(size_t)bc * 1024 + p] = xh[((size_t)(b * 1024 + p)) * 384 + ch];
}

extern "C" void kernel_launch(void* const* d_in, const int* in_sizes, int n_in,
                              void* d_out, int out_size, void* d_ws, size_t ws_size,
                              hipStream_t stream) {
    const float* x    = (const float*)d_in[0];
    const float* skip = (const float*)d_in[1];
    const float* pew  = (const float*)d_in[2];
    const float* pnw  = (const float*)d_in[3];
    const float* pnb  = (const float*)d_in[4];
    const float* lpw  = (const float*)d_in[5];
    const float* lpb  = (const float*)d_in[6];
    const float* blw  = (const float*)d_in[7];
    const float* blb  = (const float*)d_in[8];
    const float* inw  = (const float*)d_in[9];
    const float* cw   = (const float*)d_in[10];
    const float* cb   = (const float*)d_in[11];
    const float* xpw  = (const float*)d_in[12];
    const float* dtw  = (const float*)d_in[13];
    const float* dtbi = (const float*)d_in[14];
    const float* alog = (const float*)d_in[15];
    const float* ds   = (const float*)d_in[16];
    const float* onw  = (const float*)d_in[17];
    const float* onb  = (const float*)d_in[18];
    const float* ow   = (const float*)d_in[19];
    float* out = (float*)d_out;

    float* ws = (float*)d_ws;
    float* xh   = ws; ws += 2048 * 384;    // (B*L, 384) running residual
    float* hbuf = ws; ws += 2048 * 768;    // LN-out / concat-in / gated g
    float* xz   = ws; ws += 2048 * 1536;   // in_proj out (xc | z)
    float* xc   = ws; ws += 2048 * 768;    // conv+silu out (NHWC)
    float* dbl  = ws; ws += 8192 * 56;     // x_proj out, scan order
    float* dtb  = ws; ws += 8192 * 768;    // softplus(dt), scan order
    float* y4   = ws; ws += 8192 * 768;    // per-direction scan out, spatial order
    float* t1   = y4;                      // stage-A aliases (disjoint in time)
    float* xspe = y4 + 786432;

    // ---- Stage A: patch-expand + LN + concat skip + linear ----
    transpose_x_k<<<512, 256, 0, stream>>>(x, xspe);
    gemm_nt<<<dim3(1536 / 64, 512 / 64), 256, 0, stream>>>(
        xspe, pew, nullptr, nullptr, t1, 512, 1536, 768);
    pe_concat_k<<<2048, 256, 0, stream>>>(t1, skip, pnw, pnb, hbuf);
    gemm_nt<<<dim3(384 / 64, 2048 / 64), 256, 0, stream>>>(
        hbuf, lpw, lpb, nullptr, xh, 2048, 384, 768);

    // ---- 2 VSS blocks ----
    for (int blk = 0; blk < 2; ++blk) {
        const float* inw_i = inw + (size_t)blk * 1536 * 384;
        const float* cw_i  = cw + (size_t)blk * 768 * 9;
        const float* cb_i  = cb + (size_t)blk * 768;
        const float* xpw_i = xpw + (size_t)blk * 4 * 56 * 768;
        const float* dtw_i = dtw + (size_t)blk * 4 * 768 * 24;
        const float* dtb_i = dtbi + (size_t)blk * 4 * 768;
        const float* al_i  = alog + (size_t)blk * 4 * 768 * 16;
        const float* ds_i  = ds + (size_t)blk * 4 * 768;
        const float* onw_i = onw + (size_t)blk * 768;
        const float* onb_i = onb + (size_t)blk * 768;
        const float* ow_i  = ow + (size_t)blk * 384 * 768;

        ln_rows_384<<<2048, 256, 0, stream>>>(xh, blw + blk * 384, blb + blk * 384, hbuf);
        gemm_nt<<<dim3(1536 / 64, 2048 / 64), 256, 0, stream>>>(
            hbuf, inw_i, nullptr, nullptr, xz, 2048, 1536, 384);
        conv_silu_k<<<2048, 256, 0, stream>>>(xz, cw_i, cb_i, xc);
        xproj_k<<<dim3(256, 4), 64, 0, stream>>>(xc, xpw_i, dbl);
        dtproj_k<<<1024, 256, 0, stream>>>(dbl, dtw_i, dtb_i, dtb);
        scan_k<<<dim3(48, 4, 2), 256, 0, stream>>>(dtb, dbl, xc, al_i, y4);
        fuse_out_k<<<2048, 256, 0, stream>>>(y4, xc, xz, ds_i, onw_i, onb_i, hbuf);
        gemm_nt<<<dim3(384 / 64, 2048 / 64), 256, 0, stream>>>(
            hbuf, ow_i, nullptr, xh, xh, 2048, 384, 768);
    }

    out_tr_k<<<768, 256, 0, stream>>>(xh, out);
}

// Round 2
// 1021.242 us; speedup vs baseline: 1.2179x; 1.2179x over previous
//
#include <hip/hip_runtime.h>
#include <math.h>

// Problem constants: B=2, H=W=32 (after expand), L=1024, out_dim=384, Di=768,
// K=4 directions, N=16 state, R=24, depth=2. All tensors fp32.

static __device__ __forceinline__ float sigmoidf_(float x) {
    return 1.f / (1.f + __expf(-x));
}

// Scan-order <-> spatial-position map. Involution for all k:
// k=0: identity; k=1: (row,col) transpose; k=2: reverse; k=3: reverse∘transpose.
static __device__ __forceinline__ int scan_pos(int k, int l) {
    int m = (k & 2) ? (1023 - l) : l;
    return (k & 1) ? (((m & 31) << 5) | (m >> 5)) : m;
}

// ---------------- transpose x: (B,768,256) NCHW -> (B*256, 768) rows ----------------
__global__ __launch_bounds__(256) void transpose_x_k(const float* __restrict__ x,
                                                     float* __restrict__ o) {
    int m = blockIdx.x;              // 0..511  (b*256 + ij)
    int b = m >> 8, ij = m & 255;
    for (int c = threadIdx.x; c < 768; c += 256)
        o[(size_t)m * 768 + c] = x[((size_t)(b * 768 + c)) * 256 + ij];
}

// ---------------- generic NT GEMM: C[m,n] = sum_k A[m,k]*B[n,k] (+bias[n]) (+res[m,n]) ----
// A: MxK row-major, B: NxK row-major. M%64==0, N%64==0, K%16==0.
__global__ __launch_bounds__(256) void gemm_nt(const float* __restrict__ A,
                                               const float* __restrict__ B,
                                               const float* __restrict__ bias,
                                               const float* __restrict__ res,
                                               float* __restrict__ C,
                                               int M, int N, int K) {
    __shared__ float As[16][68];
    __shared__ float Bs[16][68];
    int tid = threadIdx.x;
    int bm = blockIdx.y * 64, bn = blockIdx.x * 64;
    int tx = tid & 15, ty = tid >> 4;
    int lk = tid & 15, lm = tid >> 4;
    float acc[4][4] = {};
    const float* Ap = A + (size_t)(bm + lm) * K + lk;
    const float* Bp = B + (size_t)(bn + lm) * K + lk;
    for (int k0 = 0; k0 < K; k0 += 16) {
#pragma unroll
        for (int i = 0; i < 4; ++i) {
            As[lk][lm + 16 * i] = Ap[(size_t)(16 * i) * K + k0];
            Bs[lk][lm + 16 * i] = Bp[(size_t)(16 * i) * K + k0];
        }
        __syncthreads();
#pragma unroll
        for (int kk = 0; kk < 16; ++kk) {
            float4 av = *(const float4*)&As[kk][ty * 4];
            float4 bv = *(const float4*)&Bs[kk][tx * 4];
            float a[4] = {av.x, av.y, av.z, av.w};
            float bb[4] = {bv.x, bv.y, bv.z, bv.w};
#pragma unroll
            for (int i = 0; i < 4; ++i)
#pragma unroll
                for (int j = 0; j < 4; ++j) acc[i][j] += a[i] * bb[j];
        }
        __syncthreads();
    }
#pragma unroll
    for (int i = 0; i < 4; ++i) {
        int m = bm + ty * 4 + i;
#pragma unroll
        for (int j = 0; j < 4; ++j) {
            int n = bn + tx * 4 + j;
            float v = acc[i][j];
            if (bias) v += bias[n];
            if (res) v += res[(size_t)m * N + n];
            C[(size_t)m * N + n] = v;
        }
    }
}

// ---------------- pixel-shuffle LN + skip concat: builds cin (2048, 768) ----------------
__global__ __launch_bounds__(256) void pe_concat_k(const float* __restrict__ t1,
                                                   const float* __restrict__ skip,
                                                   const float* __restrict__ pnw,
                                                   const float* __restrict__ pnb,
                                                   float* __restrict__ cin) {
    __shared__ float sh1[256], sh2[256];
    int row = blockIdx.x;           // (b*1024 + p)
    int b = row >> 10, p = row & 1023;
    int r = p >> 5, col = p & 31;
    int i = r >> 1, a = r & 1, j = col >> 1, b2 = col & 1;
    const float* src = t1 + ((size_t)(b * 256 + i * 16 + j)) * 1536 + (a * 2 + b2) * 384;
    int t = threadIdx.x;
    float v0 = src[t];
    float v1 = (t < 128) ? src[t + 256] : 0.f;
    float s1 = v0 + v1, s2 = v0 * v0 + v1 * v1;
    sh1[t] = s1; sh2[t] = s2; __syncthreads();
    for (int s = 128; s > 0; s >>= 1) {
        if (t < s) { sh1[t] += sh1[t + s]; sh2[t] += sh2[t + s]; }
        __syncthreads();
    }
    float mean = sh1[0] * (1.f / 384.f);
    float var = sh2[0] * (1.f / 384.f) - mean * mean;
    float rstd = rsqrtf(var + 1e-5f);
    float* o = cin + (size_t)row * 768;
    o[t] = (v0 - mean) * rstd * pnw[t] + pnb[t];
    if (t < 128) o[t + 256] = (v1 - mean) * rstd * pnw[t + 256] + pnb[t + 256];
    o[384 + t] = skip[((size_t)(b * 384 + t)) * 1024 + p];
    if (t < 128) o[384 + t + 256] = skip[((size_t)(b * 384 + t + 256)) * 1024 + p];
}

// ---------------- row LayerNorm over 384 cols ----------------
__global__ __launch_bounds__(256) void ln_rows_384(const float* __restrict__ in,
                                                   const float* __restrict__ w,
                                                   const float* __restrict__ b,
                                                   float* __restrict__ out) {
    __shared__ float sh1[256], sh2[256];
    int row = blockIdx.x;
    const float* x = in + (size_t)row * 384;
    int t = threadIdx.x;
    float v0 = x[t];
    float v1 = (t < 128) ? x[t + 256] : 0.f;
    float s1 = v0 + v1, s2 = v0 * v0 + v1 * v1;
    sh1[t] = s1; sh2[t] = s2; __syncthreads();
    for (int s = 128; s > 0; s >>= 1) {
        if (t < s) { sh1[t] += sh1[t + s]; sh2[t] += sh2[t + s]; }
        __syncthreads();
    }
    float mean = sh1[0] * (1.f / 384.f);
    float var = sh2[0] * (1.f / 384.f) - mean * mean;
    float rstd = rsqrtf(var + 1e-5f);
    out[(size_t)row * 384 + t] = (v0 - mean) * rstd * w[t] + b[t];
    if (t < 128)
        out[(size_t)row * 384 + t + 256] = (v1 - mean) * rstd * w[t + 256] + b[t + 256];
}

// ---------------- depthwise 3x3 conv (SAME) + bias + SiLU. In: xz cols [0,768) ----------
__global__ __launch_bounds__(256) void conv_silu_k(const float* __restrict__ xz,
                                                   const float* __restrict__ cw,
                                                   const float* __restrict__ cb,
                                                   float* __restrict__ xc) {
    int row = blockIdx.x;
    int b = row >> 10, p = row & 1023;
    int r = p >> 5, col = p & 31;
    for (int d = threadIdx.x; d < 768; d += 256) {
        float acc = cb[d];
#pragma unroll
        for (int dy = 0; dy < 3; ++dy) {
            int rr = r + dy - 1;
            if ((unsigned)rr > 31u) continue;
#pragma unroll
            for (int dx = 0; dx < 3; ++dx) {
                int cc = col + dx - 1;
                if ((unsigned)cc > 31u) continue;
                acc += cw[d * 9 + dy * 3 + dx] *
                       xz[((size_t)(b * 1024 + rr * 32 + cc)) * 1536 + d];
            }
        }
        xc[(size_t)row * 768 + d] = acc * sigmoidf_(acc);
    }
}

// ---------------- x_proj: dbl[b,k,l,0..56) = xp[k] @ xc[pos] , stored in scan order ------
__global__ __launch_bounds__(64) void xproj_k(const float* __restrict__ xc,
                                              const float* __restrict__ xpw,
                                              float* __restrict__ dbl) {
    __shared__ float xs[8][768];
    int k = blockIdx.y;
    int p0 = blockIdx.x * 8;        // global row in [0,2048), 8 rows share b
    const float4* src = (const float4*)(xc + (size_t)p0 * 768);
    float4* dst = (float4*)xs;
    for (int i = threadIdx.x; i < 8 * 768 / 4; i += 64) dst[i] = src[i];
    __syncthreads();
    int c = threadIdx.x;
    if (c >= 56) return;
    const float* w = xpw + ((size_t)(k * 56 + c)) * 768;
    float acc[8] = {};
    for (int q = 0; q < 768; q += 4) {
        float4 wv = *(const float4*)(w + q);
#pragma unroll
        for (int i = 0; i < 8; ++i) {
            float4 xv = *(const float4*)&xs[i][q];
            acc[i] += wv.x * xv.x + wv.y * xv.y + wv.z * xv.z + wv.w * xv.w;
        }
    }
    int b = p0 >> 10;
#pragma unroll
    for (int i = 0; i < 8; ++i) {
        int pp = (p0 + i) & 1023;
        int l = scan_pos(k, pp);    // involution: l(p) == p(l) formula
        dbl[(((size_t)(b * 4 + k)) * 1024 + l) * 56 + c] = acc[i];
    }
}

// ---------------- dt_proj + softplus: dt[b,k,l,d] (scan order) ----------------
__global__ __launch_bounds__(256) void dtproj_k(const float* __restrict__ dbl,
                                                const float* __restrict__ dtw,
                                                const float* __restrict__ dtbias,
                                                float* __restrict__ dt) {
    __shared__ float dr[8][24];
    int row0 = blockIdx.x * 8;      // global over B*K*L = 8192
    int k = (row0 >> 10) & 3;
    for (int i = threadIdx.x; i < 192; i += 256)
        dr[i / 24][i % 24] = dbl[(size_t)(row0 + i / 24) * 56 + (i % 24)];
    __syncthreads();
    int t = threadIdx.x;
#pragma unroll
    for (int j = 0; j < 3; ++j) {
        int d = t + j * 256;
        const float* w = dtw + ((size_t)(k * 768 + d)) * 24;
        float wv[24];
#pragma unroll
        for (int r = 0; r < 24; ++r) wv[r] = w[r];
        float bias = dtbias[k * 768 + d];
#pragma unroll
        for (int i = 0; i < 8; ++i) {
            float acc = bias;
#pragma unroll
            for (int r = 0; r < 24; ++r) acc += wv[r] * dr[i][r];
            float sp = (acc > 20.f) ? acc : log1pf(__expf(acc));
            dt[(size_t)(row0 + i) * 768 + d] = sp;
        }
    }
}

// ---------------- selective scan, LDS-chunked + double-buffered ----------------
// Block: 128 threads = 8 chains (d) x 16 lanes (n). Grid (96, 4, 2) = 768 blocks
// -> 3 blocks/CU evenly. Per 32-step chunk: block-coalesced float4 staging of
// dt/u/B/C into LDS (issued one chunk ahead), then 32 register-speed recurrence
// steps. Amortizes the ~800-cycle memory latency that made v1 816 cyc/step.
__global__ __launch_bounds__(128) void scan_k(const float* __restrict__ dt,
                                              const float* __restrict__ dbl,
                                              const float* __restrict__ xc,
                                              const float* __restrict__ alog,
                                              float* __restrict__ y4) {
    __shared__ __align__(16) float sdt[2][32][8];
    __shared__ __align__(16) float su[2][32][8];
    __shared__ __align__(16) float sB[2][32][16];
    __shared__ __align__(16) float sC[2][32][16];
    int t = threadIdx.x;
    int n = t & 15, chain = t >> 4;          // chain in [0,8)
    int d0 = blockIdx.x * 8;
    int k = blockIdx.y, b = blockIdx.z;
    int d = d0 + chain;
    // A = -exp(A_log); fold log2(e) so the recurrence uses v_exp_f32 directly.
    float A2 = -__expf(alog[((size_t)(k * 768 + d)) * 16 + n]) * 1.44269504f;
    const float* dtp = dt + (((size_t)(b * 4 + k)) * 1024) * 768;
    const float* dbp = dbl + (((size_t)(b * 4 + k)) * 1024) * 56;
    const float* xp  = xc + (size_t)b * 1024 * 768;
    float* yp = y4 + (((size_t)(b * 4 + k)) * 1024) * 768;

    // load-assignment indices (fixed per thread)
    int ib = t >> 2, qb = (t & 3) * 4;       // B/C: 32 steps x 4 float4 each
    int tt = t & 63, ia = tt >> 1, qa = (tt & 1) * 4;  // dt or u: 32 steps x 2 float4

    float4 rB, rC, rA;
    auto issue = [&](int c) {
        int l0 = c * 32;
        rB = *(const float4*)&dbp[(size_t)(l0 + ib) * 56 + 24 + qb];
        rC = *(const float4*)&dbp[(size_t)(l0 + ib) * 56 + 40 + qb];
        if (t < 64) {
            rA = *(const float4*)&dtp[(size_t)(l0 + ia) * 768 + d0 + qa];
        } else {
            int p = scan_pos(k, l0 + ia);
            rA = *(const float4*)&xp[(size_t)p * 768 + d0 + qa];
        }
    };
    auto commit = [&](int buf) {
        *(float4*)&sB[buf][ib][qb] = rB;
        *(float4*)&sC[buf][ib][qb] = rC;
        if (t < 64) *(float4*)&sdt[buf][ia][qa] = rA;
        else        *(float4*)&su[buf][ia][qa] = rA;
    };

    issue(0);
    commit(0);
    float h = 0.f;
    for (int c = 0; c < 32; ++c) {
        int buf = c & 1;
        if (c + 1 < 32) issue(c + 1);        // overlap next chunk's latency
        __syncthreads();                      // LDS[buf] ready for all
        int l0 = c * 32;
#pragma unroll 8
        for (int i = 0; i < 32; ++i) {
            float dtv = sdt[buf][i][chain];
            float uv  = su[buf][i][chain];
            float Bv  = sB[buf][i][n];
            float Cv  = sC[buf][i][n];
            float a = __builtin_amdgcn_exp2f(dtv * A2);
            h = a * h + dtv * uv * Bv;
            float part = h * Cv;
            part += __shfl_xor(part, 1);
            part += __shfl_xor(part, 2);
            part += __shfl_xor(part, 4);
            part += __shfl_xor(part, 8);
            if (n == 0) {
                int p = scan_pos(k, l0 + i);
                yp[(size_t)p * 768 + d0 + chain] = part;
            }
        }
        if (c + 1 < 32) commit(buf ^ 1);     // barrier at next-iter top orders this
    }
}

// ---------------- sum 4 directions + D*u, out-LN, * silu(z) -> g ----------------
__global__ __launch_bounds__(256) void fuse_out_k(const float* __restrict__ y4,
                                                  const float* __restrict__ xc,
                                                  const float* __restrict__ xz,
                                                  const float* __restrict__ ds,
                                                  const float* __restrict__ onw,
                                                  const float* __restrict__ onb,
                                                  float* __restrict__ g) {
    __shared__ float sh1[256], sh2[256];
    int row = blockIdx.x;
    int b = row >> 10, p = row & 1023;
    int t = threadIdx.x;
    float vals[3];
    float s1 = 0.f, s2 = 0.f;
#pragma unroll
    for (int j = 0; j < 3; ++j) {
        int d = t + j * 256;
        float u = xc[(size_t)row * 768 + d];
        float dsum = ds[d] + ds[768 + d] + ds[1536 + d] + ds[2304 + d];
        float v = dsum * u;
#pragma unroll
        for (int k = 0; k < 4; ++k)
            v += y4[(((size_t)(b * 4 + k)) * 1024 + p) * 768 + d];
        vals[j] = v; s1 += v; s2 += v * v;
    }
    sh1[t] = s1; sh2[t] = s2; __syncthreads();
    for (int s = 128; s > 0; s >>= 1) {
        if (t < s) { sh1[t] += sh1[t + s]; sh2[t] += sh2[t + s]; }
        __syncthreads();
    }
    float mean = sh1[0] * (1.f / 768.f);
    float var = sh2[0] * (1.f / 768.f) - mean * mean;
    float rstd = rsqrtf(var + 1e-5f);
#pragma unroll
    for (int j = 0; j < 3; ++j) {
        int d = t + j * 256;
        float zz = xz[(size_t)row * 1536 + 768 + d];
        float sil = zz * sigmoidf_(zz);
        g[(size_t)row * 768 + d] = ((vals[j] - mean) * rstd * onw[d] + onb[d]) * sil;
    }
}

// ---------------- final: (B*L,384) -> (B,384,32,32) ----------------
__global__ __launch_bounds__(256) void out_tr_k(const float* __restrict__ xh,
                                                float* __restrict__ out) {
    int bc = blockIdx.x;            // 0..767 (b*384 + ch)
    int b = bc / 384, ch = bc % 384;
    for (int p = threadIdx.x; p < 1024; p += 256)
        out[(size_t)bc * 1024 + p] = xh[((size_t)(b * 1024 + p)) * 384 + ch];
}

extern "C" void kernel_launch(void* const* d_in, const int* in_sizes, int n_in,
                              void* d_out, int out_size, void* d_ws, size_t ws_size,
                              hipStream_t stream) {
    const float* x    = (const float*)d_in[0];
    const float* skip = (const float*)d_in[1];
    const float* pew  = (const float*)d_in[2];
    const float* pnw  = (const float*)d_in[3];
    const float* pnb  = (const float*)d_in[4];
    const float* lpw  = (const float*)d_in[5];
    const float* lpb  = (const float*)d_in[6];
    const float* blw  = (const float*)d_in[7];
    const float* blb  = (const float*)d_in[8];
    const float* inw  = (const float*)d_in[9];
    const float* cw   = (const float*)d_in[10];
    const float* cb   = (const float*)d_in[11];
    const float* xpw  = (const float*)d_in[12];
    const float* dtw  = (const float*)d_in[13];
    const float* dtbi = (const float*)d_in[14];
    const float* alog = (const float*)d_in[15];
    const float* ds   = (const float*)d_in[16];
    const float* onw  = (const float*)d_in[17];
    const float* onb  = (const float*)d_in[18];
    const float* ow   = (const float*)d_in[19];
    float* out = (float*)d_out;

    float* ws = (float*)d_ws;
    float* xh   = ws; ws += 2048 * 384;    // (B*L, 384) running residual
    float* hbuf = ws; ws += 2048 * 768;    // LN-out / concat-in / gated g
    float* xz   = ws; ws += 2048 * 1536;   // in_proj out (xc | z)
    float* xc   = ws; ws += 2048 * 768;    // conv+silu out (NHWC)
    float* dbl  = ws; ws += 8192 * 56;     // x_proj out, scan order
    float* dtb  = ws; ws += 8192 * 768;    // softplus(dt), scan order
    float* y4   = ws; ws += 8192 * 768;    // per-direction scan out, spatial order
    float* t1   = y4;                      // stage-A aliases (disjoint in time)
    float* xspe = y4 + 786432;

    // ---- Stage A: patch-expand + LN + concat skip + linear ----
    transpose_x_k<<<512, 256, 0, stream>>>(x, xspe);
    gemm_nt<<<dim3(1536 / 64, 512 / 64), 256, 0, stream>>>(
        xspe, pew, nullptr, nullptr, t1, 512, 1536, 768);
    pe_concat_k<<<2048, 256, 0, stream>>>(t1, skip, pnw, pnb, hbuf);
    gemm_nt<<<dim3(384 / 64, 2048 / 64), 256, 0, stream>>>(
        hbuf, lpw, lpb, nullptr, xh, 2048, 384, 768);

    // ---- 2 VSS blocks ----
    for (int blk = 0; blk < 2; ++blk) {
        const float* inw_i = inw + (size_t)blk * 1536 * 384;
        const float* cw_i  = cw + (size_t)blk * 768 * 9;
        const float* cb_i  = cb + (size_t)blk * 768;
        const float* xpw_i = xpw + (size_t)blk * 4 * 56 * 768;
        const float* dtw_i = dtw + (size_t)blk * 4 * 768 * 24;
        const float* dtb_i = dtbi + (size_t)blk * 4 * 768;
        const float* al_i  = alog + (size_t)blk * 4 * 768 * 16;
        const float* ds_i  = ds + (size_t)blk * 4 * 768;
        const float* onw_i = onw + (size_t)blk * 768;
        const float* onb_i = onb + (size_t)blk * 768;
        const float* ow_i  = ow + (size_t)blk * 384 * 768;

        ln_rows_384<<<2048, 256, 0, stream>>>(xh, blw + blk * 384, blb + blk * 384, hbuf);
        gemm_nt<<<dim3(1536 / 64, 2048 / 64), 256, 0, stream>>>(
            hbuf, inw_i, nullptr, nullptr, xz, 2048, 1536, 384);
        conv_silu_k<<<2048, 256, 0, stream>>>(xz, cw_i, cb_i, xc);
        xproj_k<<<dim3(256, 4), 64, 0, stream>>>(xc, xpw_i, dbl);
        dtproj_k<<<1024, 256, 0, stream>>>(dbl, dtw_i, dtb_i, dtb);
        scan_k<<<dim3(96, 4, 2), 128, 0, stream>>>(dtb, dbl, xc, al_i, y4);
        fuse_out_k<<<2048, 256, 0, stream>>>(y4, xc, xz, ds_i, onw_i, onb_i, hbuf);
        gemm_nt<<<dim3(384 / 64, 2048 / 64), 256, 0, stream>>>(
            hbuf, ow_i, nullptr, xh, xh, 2048, 384, 768);
    }

    out_tr_k<<<768, 256, 0, stream>>>(xh, out);
}

// Round 3
// 595.136 us; speedup vs baseline: 2.0898x; 1.7160x over previous
//
#include <hip/hip_runtime.h>
#include <math.h>

// Problem constants: B=2, H=W=32 (after expand), L=1024, out_dim=384, Di=768,
// K=4 directions, N=16 state, R=24, depth=2. fp32 in/out; bf16 MFMA GEMMs.

typedef __attribute__((ext_vector_type(8))) short s8v;   // 8 bf16 = 4 VGPRs
typedef __attribute__((ext_vector_type(4))) float f4v;

static __device__ __forceinline__ float sigmoidf_(float x) {
    return 1.f / (1.f + __expf(-x));
}
static __device__ __forceinline__ ushort f2bf(float x) {
    unsigned u = __float_as_uint(x);
    return (ushort)((u + 0x7fff + ((u >> 16) & 1)) >> 16);   // RNE
}

// Scan-order <-> spatial-position map. Involution for all k.
static __device__ __forceinline__ int scan_pos(int k, int l) {
    int m = (k & 2) ? (1023 - l) : l;
    return (k & 1) ? (((m & 31) << 5) | (m >> 5)) : m;
}

// ---------------- f32 -> bf16 convert (weights), float4-vectorized ----------------
__global__ __launch_bounds__(256) void cvt_k(const float* __restrict__ s,
                                             ushort* __restrict__ d, int n4) {
    int i = blockIdx.x * 256 + threadIdx.x;
    int stride = gridDim.x * 256;
    for (; i < n4; i += stride) {
        float4 v = ((const float4*)s)[i];
        ushort4 o = {f2bf(v.x), f2bf(v.y), f2bf(v.z), f2bf(v.w)};
        ((ushort4*)d)[i] = o;
    }
}

// ---------------- transpose x: (B,768,256) NCHW -> (B*256, 768) bf16 rows --------
__global__ __launch_bounds__(256) void transpose_x_k(const float* __restrict__ x,
                                                     ushort* __restrict__ o) {
    int m = blockIdx.x;              // 0..511  (b*256 + ij)
    int b = m >> 8, ij = m & 255;
    for (int c = threadIdx.x; c < 768; c += 256)
        o[(size_t)m * 768 + c] = f2bf(x[((size_t)(b * 768 + c)) * 256 + ij]);
}

// ---------------- bf16 NT MFMA GEMM: C[m,n] = sum_k A[m,k]*B[n,k] (+bias)(+res) --
// A: MxK bf16 row-major, B: NxK bf16 row-major, C fp32. M%128==0 (or 512),
// N%128==0, K%32==0. Block 256 = 4 waves in 2x2; wave does 64x64 via 4x4 MFMA
// tiles of 16x16x32. LDS rows padded to 40 bf16 (80 B = 20 banks -> worst 2-way,
// free per m136).
__global__ __launch_bounds__(256) void gemm_bf(const ushort* __restrict__ A,
                                               const ushort* __restrict__ B,
                                               const float* __restrict__ bias,
                                               const float* __restrict__ res,
                                               float* __restrict__ C,
                                               int M, int N, int K) {
    __shared__ ushort Als[128][40];
    __shared__ ushort Bls[128][40];
    int t = threadIdx.x;
    int bm = blockIdx.y * 128, bn = blockIdx.x * 128;
    int lane = t & 63, w = t >> 6;
    int wm = (w & 1) * 64, wn = (w >> 1) * 64;
    int r16 = lane & 15, quad = lane >> 4;
    int srow = t >> 1, shalf = t & 1;        // staging: 2 threads/row, 32 B each
    f4v acc[4][4] = {};
    const ushort* Ag = A + (size_t)(bm + srow) * K + shalf * 16;
    const ushort* Bg = B + (size_t)(bn + srow) * K + shalf * 16;
    for (int k0 = 0; k0 < K; k0 += 32) {
        uint4 a0 = *(const uint4*)(Ag + k0);
        uint4 a1 = *(const uint4*)(Ag + k0 + 8);
        uint4 b0 = *(const uint4*)(Bg + k0);
        uint4 b1 = *(const uint4*)(Bg + k0 + 8);
        __syncthreads();                      // previous iter's reads done
        *(uint4*)&Als[srow][shalf * 16] = a0;
        *(uint4*)&Als[srow][shalf * 16 + 8] = a1;
        *(uint4*)&Bls[srow][shalf * 16] = b0;
        *(uint4*)&Bls[srow][shalf * 16 + 8] = b1;
        __syncthreads();
        s8v af[4], bfr[4];
#pragma unroll
        for (int i = 0; i < 4; ++i) {
            af[i]  = *(const s8v*)&Als[wm + i * 16 + r16][quad * 8];
            bfr[i] = *(const s8v*)&Bls[wn + i * 16 + r16][quad * 8];
        }
#pragma unroll
        for (int i = 0; i < 4; ++i)
#pragma unroll
            for (int j = 0; j < 4; ++j)
                acc[i][j] = __builtin_amdgcn_mfma_f32_16x16x32_bf16(
                    af[i], bfr[j], acc[i][j], 0, 0, 0);
    }
    // epilogue: D mapping col=lane&15, row=quad*4+reg (m89-verified)
#pragma unroll
    for (int i = 0; i < 4; ++i) {
        int row0 = bm + wm + i * 16 + quad * 4;
#pragma unroll
        for (int j = 0; j < 4; ++j) {
            int col = bn + wn + j * 16 + r16;
            float bv = bias ? bias[col] : 0.f;
#pragma unroll
            for (int r = 0; r < 4; ++r) {
                int row = row0 + r;
                float v = acc[i][j][r] + bv;
                if (res) v += res[(size_t)row * N + col];
                C[(size_t)row * N + col] = v;
            }
        }
    }
}

// ---------------- pixel-shuffle LN + skip concat -> cin (2048, 768) bf16 ---------
__global__ __launch_bounds__(256) void pe_concat_k(const float* __restrict__ t1,
                                                   const float* __restrict__ skip,
                                                   const float* __restrict__ pnw,
                                                   const float* __restrict__ pnb,
                                                   ushort* __restrict__ cin) {
    __shared__ float sh1[256], sh2[256];
    int row = blockIdx.x;           // (b*1024 + p)
    int b = row >> 10, p = row & 1023;
    int r = p >> 5, col = p & 31;
    int i = r >> 1, a = r & 1, j = col >> 1, b2 = col & 1;
    const float* src = t1 + ((size_t)(b * 256 + i * 16 + j)) * 1536 + (a * 2 + b2) * 384;
    int t = threadIdx.x;
    float v0 = src[t];
    float v1 = (t < 128) ? src[t + 256] : 0.f;
    float s1 = v0 + v1, s2 = v0 * v0 + v1 * v1;
    sh1[t] = s1; sh2[t] = s2; __syncthreads();
    for (int s = 128; s > 0; s >>= 1) {
        if (t < s) { sh1[t] += sh1[t + s]; sh2[t] += sh2[t + s]; }
        __syncthreads();
    }
    float mean = sh1[0] * (1.f / 384.f);
    float var = sh2[0] * (1.f / 384.f) - mean * mean;
    float rstd = rsqrtf(var + 1e-5f);
    ushort* o = cin + (size_t)row * 768;
    o[t] = f2bf((v0 - mean) * rstd * pnw[t] + pnb[t]);
    if (t < 128) o[t + 256] = f2bf((v1 - mean) * rstd * pnw[t + 256] + pnb[t + 256]);
    o[384 + t] = f2bf(skip[((size_t)(b * 384 + t)) * 1024 + p]);
    if (t < 128)
        o[384 + t + 256] = f2bf(skip[((size_t)(b * 384 + t + 256)) * 1024 + p]);
}

// ---------------- row LayerNorm over 384 cols -> bf16 ----------------
__global__ __launch_bounds__(256) void ln_rows_384(const float* __restrict__ in,
                                                   const float* __restrict__ w,
                                                   const float* __restrict__ b,
                                                   ushort* __restrict__ out) {
    __shared__ float sh1[256], sh2[256];
    int row = blockIdx.x;
    const float* x = in + (size_t)row * 384;
    int t = threadIdx.x;
    float v0 = x[t];
    float v1 = (t < 128) ? x[t + 256] : 0.f;
    float s1 = v0 + v1, s2 = v0 * v0 + v1 * v1;
    sh1[t] = s1; sh2[t] = s2; __syncthreads();
    for (int s = 128; s > 0; s >>= 1) {
        if (t < s) { sh1[t] += sh1[t + s]; sh2[t] += sh2[t + s]; }
        __syncthreads();
    }
    float mean = sh1[0] * (1.f / 384.f);
    float var = sh2[0] * (1.f / 384.f) - mean * mean;
    float rstd = rsqrtf(var + 1e-5f);
    out[(size_t)row * 384 + t] = f2bf((v0 - mean) * rstd * w[t] + b[t]);
    if (t < 128)
        out[(size_t)row * 384 + t + 256] =
            f2bf((v1 - mean) * rstd * w[t + 256] + b[t + 256]);
}

// ---------------- depthwise 3x3 conv (SAME) + bias + SiLU ----------------
__global__ __launch_bounds__(256) void conv_silu_k(const float* __restrict__ xz,
                                                   const float* __restrict__ cw,
                                                   const float* __restrict__ cb,
                                                   float* __restrict__ xc) {
    int row = blockIdx.x;
    int b = row >> 10, p = row & 1023;
    int r = p >> 5, col = p & 31;
    for (int d = threadIdx.x; d < 768; d += 256) {
        float acc = cb[d];
#pragma unroll
        for (int dy = 0; dy < 3; ++dy) {
            int rr = r + dy - 1;
            if ((unsigned)rr > 31u) continue;
#pragma unroll
            for (int dx = 0; dx < 3; ++dx) {
                int cc = col + dx - 1;
                if ((unsigned)cc > 31u) continue;
                acc += cw[d * 9 + dy * 3 + dx] *
                       xz[((size_t)(b * 1024 + rr * 32 + cc)) * 1536 + d];
            }
        }
        xc[(size_t)row * 768 + d] = acc * sigmoidf_(acc);
    }
}

// ---------------- x_proj: dbl[kb,l,0..56) = xp[k] @ xc[pos], scan order ----------
__global__ __launch_bounds__(64) void xproj_k(const float* __restrict__ xc,
                                              const float* __restrict__ xpw,
                                              float* __restrict__ dbl) {
    __shared__ float xs[8][768];
    int k = blockIdx.y;
    int p0 = blockIdx.x * 8;
    const float4* src = (const float4*)(xc + (size_t)p0 * 768);
    float4* dst = (float4*)xs;
    for (int i = threadIdx.x; i < 8 * 768 / 4; i += 64) dst[i] = src[i];
    __syncthreads();
    int c = threadIdx.x;
    if (c >= 56) return;
    const float* w = xpw + ((size_t)(k * 56 + c)) * 768;
    float acc[8] = {};
    for (int q = 0; q < 768; q += 4) {
        float4 wv = *(const float4*)(w + q);
#pragma unroll
        for (int i = 0; i < 8; ++i) {
            float4 xv = *(const float4*)&xs[i][q];
            acc[i] += wv.x * xv.x + wv.y * xv.y + wv.z * xv.z + wv.w * xv.w;
        }
    }
    int b = p0 >> 10;
#pragma unroll
    for (int i = 0; i < 8; ++i) {
        int pp = (p0 + i) & 1023;
        int l = scan_pos(k, pp);
        dbl[(((size_t)(b * 4 + k)) * 1024 + l) * 56 + c] = acc[i];
    }
}

// ---------------- dt_proj + softplus: dt[kb,l,d] (scan order) ----------------
__global__ __launch_bounds__(256) void dtproj_k(const float* __restrict__ dbl,
                                                const float* __restrict__ dtw,
                                                const float* __restrict__ dtbias,
                                                float* __restrict__ dt) {
    __shared__ float dr[8][24];
    int row0 = blockIdx.x * 8;
    int k = (row0 >> 10) & 3;
    for (int i = threadIdx.x; i < 192; i += 256)
        dr[i / 24][i % 24] = dbl[(size_t)(row0 + i / 24) * 56 + (i % 24)];
    __syncthreads();
    int t = threadIdx.x;
#pragma unroll
    for (int j = 0; j < 3; ++j) {
        int d = t + j * 256;
        const float* w = dtw + ((size_t)(k * 768 + d)) * 24;
        float wv[24];
#pragma unroll
        for (int r = 0; r < 24; ++r) wv[r] = w[r];
        float bias = dtbias[k * 768 + d];
#pragma unroll
        for (int i = 0; i < 8; ++i) {
            float acc = bias;
#pragma unroll
            for (int r = 0; r < 24; ++r) acc += wv[r] * dr[i][r];
            float sp = (acc > 20.f) ? acc : log1pf(__expf(acc));
            dt[(size_t)(row0 + i) * 768 + d] = sp;
        }
    }
}

// ======== selective scan, affine-chunked over L (2 kernels, no shuffles) ========
// Thread = one d-chain with all 16 n states in registers. 16 L-chunks of 64.
// Block = 1 wave (64 d's). p1: per-chunk (P = prod a, H = h|h0=0) -> global.
// p2: prefix-combine then rescan emitting y. All loads coalesced; B (and C)
// broadcast via LDS.

__global__ __launch_bounds__(64) void scan_p1(const float* __restrict__ dt,
                                              const float* __restrict__ dbl,
                                              const float* __restrict__ xc,
                                              const float* __restrict__ alog,
                                              float* __restrict__ Pg,
                                              float* __restrict__ Hg) {
    __shared__ float sB[32][16];
    int lane = threadIdx.x;
    int d0 = blockIdx.x * 64, ch = blockIdx.y, kb = blockIdx.z;
    int k = kb & 3, b = kb >> 2;
    int d = d0 + lane;
    float A2[16];
    {
        const float4* ap = (const float4*)(alog + ((size_t)(k * 768 + d)) * 16);
#pragma unroll
        for (int q = 0; q < 4; ++q) {
            float4 v = ap[q];
            A2[4 * q + 0] = -__expf(v.x) * 1.44269504f;
            A2[4 * q + 1] = -__expf(v.y) * 1.44269504f;
            A2[4 * q + 2] = -__expf(v.z) * 1.44269504f;
            A2[4 * q + 3] = -__expf(v.w) * 1.44269504f;
        }
    }
    const float* dtp = dt + (size_t)kb * 786432 + d;
    const float* dbp = dbl + (size_t)kb * 1024 * 56;
    const float* xp  = xc + (size_t)b * 786432 + d0;
    int l0 = ch * 64;
    float h[16], P[16];
#pragma unroll
    for (int n = 0; n < 16; ++n) { h[n] = 0.f; P[n] = 1.f; }
    int bi = lane >> 4, bn_ = lane & 15;
#pragma unroll 1
    for (int w = 0; w < 2; ++w) {
        int lw = l0 + w * 32;
        float rdt[32], ru[32], rB[8];
#pragma unroll
        for (int i = 0; i < 32; ++i) rdt[i] = dtp[(size_t)(lw + i) * 768];
#pragma unroll
        for (int i = 0; i < 32; ++i) {
            int p = scan_pos(k, lw + i);
            ru[i] = xp[(size_t)p * 768 + lane];
        }
#pragma unroll
        for (int j = 0; j < 8; ++j)
            rB[j] = dbp[(size_t)(lw + bi + 4 * j) * 56 + 24 + bn_];
        __syncthreads();
#pragma unroll
        for (int j = 0; j < 8; ++j) sB[bi + 4 * j][bn_] = rB[j];
        __syncthreads();
#pragma unroll 4
        for (int i = 0; i < 32; ++i) {
            float dtv = rdt[i], dtu = dtv * ru[i];
            const float4* B4 = (const float4*)&sB[i][0];
            float4 q0 = B4[0], q1 = B4[1], q2 = B4[2], q3 = B4[3];
            float Bv[16] = {q0.x, q0.y, q0.z, q0.w, q1.x, q1.y, q1.z, q1.w,
                            q2.x, q2.y, q2.z, q2.w, q3.x, q3.y, q3.z, q3.w};
#pragma unroll
            for (int n = 0; n < 16; ++n) {
                float a = __builtin_amdgcn_exp2f(dtv * A2[n]);
                P[n] *= a;
                h[n] = a * h[n] + dtu * Bv[n];
            }
        }
    }
    float* pp = Pg + (((size_t)kb * 16 + ch) * 768 + d) * 16;
    float* hp = Hg + (((size_t)kb * 16 + ch) * 768 + d) * 16;
#pragma unroll
    for (int q = 0; q < 4; ++q) {
        float4 pv = {P[4 * q], P[4 * q + 1], P[4 * q + 2], P[4 * q + 3]};
        float4 hv = {h[4 * q], h[4 * q + 1], h[4 * q + 2], h[4 * q + 3]};
        *(float4*)(pp + 4 * q) = pv;
        *(float4*)(hp + 4 * q) = hv;
    }
}

__global__ __launch_bounds__(64) void scan_p2(const float* __restrict__ dt,
                                              const float* __restrict__ dbl,
                                              const float* __restrict__ xc,
                                              const float* __restrict__ alog,
                                              const float* __restrict__ Pg,
                                              const float* __restrict__ Hg,
                                              float* __restrict__ y4) {
    __shared__ float sB[32][16];
    __shared__ float sC[32][16];
    int lane = threadIdx.x;
    int d0 = blockIdx.x * 64, ch = blockIdx.y, kb = blockIdx.z;
    int k = kb & 3, b = kb >> 2;
    int d = d0 + lane;
    float A2[16];
    {
        const float4* ap = (const float4*)(alog + ((size_t)(k * 768 + d)) * 16);
#pragma unroll
        for (int q = 0; q < 4; ++q) {
            float4 v = ap[q];
            A2[4 * q + 0] = -__expf(v.x) * 1.44269504f;
            A2[4 * q + 1] = -__expf(v.y) * 1.44269504f;
            A2[4 * q + 2] = -__expf(v.z) * 1.44269504f;
            A2[4 * q + 3] = -__expf(v.w) * 1.44269504f;
        }
    }
    // prefix: h0 = state after chunks 0..ch-1
    float h[16];
#pragma unroll
    for (int n = 0; n < 16; ++n) h[n] = 0.f;
    for (int j = 0; j < ch; ++j) {
        const float4* pj = (const float4*)(Pg + (((size_t)kb * 16 + j) * 768 + d) * 16);
        const float4* hj = (const float4*)(Hg + (((size_t)kb * 16 + j) * 768 + d) * 16);
#pragma unroll
        for (int q = 0; q < 4; ++q) {
            float4 pv = pj[q], hv = hj[q];
            h[4 * q + 0] = pv.x * h[4 * q + 0] + hv.x;
            h[4 * q + 1] = pv.y * h[4 * q + 1] + hv.y;
            h[4 * q + 2] = pv.z * h[4 * q + 2] + hv.z;
            h[4 * q + 3] = pv.w * h[4 * q + 3] + hv.w;
        }
    }
    const float* dtp = dt + (size_t)kb * 786432 + d;
    const float* dbp = dbl + (size_t)kb * 1024 * 56;
    const float* xp  = xc + (size_t)b * 786432 + d0;
    float* yp = y4 + (size_t)kb * 786432 + d;
    int l0 = ch * 64;
    int bi = lane >> 4, bn_ = lane & 15;
#pragma unroll 1
    for (int w = 0; w < 2; ++w) {
        int lw = l0 + w * 32;
        float rdt[32], ru[32], rB[8], rC[8];
#pragma unroll
        for (int i = 0; i < 32; ++i) rdt[i] = dtp[(size_t)(lw + i) * 768];
#pragma unroll
        for (int i = 0; i < 32; ++i) {
            int p = scan_pos(k, lw + i);
            ru[i] = xp[(size_t)p * 768 + lane];
        }
#pragma unroll
        for (int j = 0; j < 8; ++j) {
            rB[j] = dbp[(size_t)(lw + bi + 4 * j) * 56 + 24 + bn_];
            rC[j] = dbp[(size_t)(lw + bi + 4 * j) * 56 + 40 + bn_];
        }
        __syncthreads();
#pragma unroll
        for (int j = 0; j < 8; ++j) {
            sB[bi + 4 * j][bn_] = rB[j];
            sC[bi + 4 * j][bn_] = rC[j];
        }
        __syncthreads();
#pragma unroll 4
        for (int i = 0; i < 32; ++i) {
            float dtv = rdt[i], dtu = dtv * ru[i];
            const float4* B4 = (const float4*)&sB[i][0];
            const float4* C4 = (const float4*)&sC[i][0];
            float4 q0 = B4[0], q1 = B4[1], q2 = B4[2], q3 = B4[3];
            float Bv[16] = {q0.x, q0.y, q0.z, q0.w, q1.x, q1.y, q1.z, q1.w,
                            q2.x, q2.y, q2.z, q2.w, q3.x, q3.y, q3.z, q3.w};
            float4 c0 = C4[0], c1 = C4[1], c2 = C4[2], c3 = C4[3];
            float Cv[16] = {c0.x, c0.y, c0.z, c0.w, c1.x, c1.y, c1.z, c1.w,
                            c2.x, c2.y, c2.z, c2.w, c3.x, c3.y, c3.z, c3.w};
            float y = 0.f;
#pragma unroll
            for (int n = 0; n < 16; ++n) {
                float a = __builtin_amdgcn_exp2f(dtv * A2[n]);
                h[n] = a * h[n] + dtu * Bv[n];
                y += h[n] * Cv[n];
            }
            int p = scan_pos(k, lw + i);
            yp[(size_t)p * 768] = y;
        }
    }
}

// ---------------- sum 4 directions + D*u, out-LN, * silu(z) -> g (bf16) ----------
__global__ __launch_bounds__(256) void fuse_out_k(const float* __restrict__ y4,
                                                  const float* __restrict__ xc,
                                                  const float* __restrict__ xz,
                                                  const float* __restrict__ ds,
                                                  const float* __restrict__ onw,
                                                  const float* __restrict__ onb,
                                                  ushort* __restrict__ g) {
    __shared__ float sh1[256], sh2[256];
    int row = blockIdx.x;
    int b = row >> 10, p = row & 1023;
    int t = threadIdx.x;
    float vals[3];
    float s1 = 0.f, s2 = 0.f;
#pragma unroll
    for (int j = 0; j < 3; ++j) {
        int d = t + j * 256;
        float u = xc[(size_t)row * 768 + d];
        float dsum = ds[d] + ds[768 + d] + ds[1536 + d] + ds[2304 + d];
        float v = dsum * u;
#pragma unroll
        for (int k = 0; k < 4; ++k)
            v += y4[(((size_t)(b * 4 + k)) * 1024 + p) * 768 + d];
        vals[j] = v; s1 += v; s2 += v * v;
    }
    sh1[t] = s1; sh2[t] = s2; __syncthreads();
    for (int s = 128; s > 0; s >>= 1) {
        if (t < s) { sh1[t] += sh1[t + s]; sh2[t] += sh2[t + s]; }
        __syncthreads();
    }
    float mean = sh1[0] * (1.f / 768.f);
    float var = sh2[0] * (1.f / 768.f) - mean * mean;
    float rstd = rsqrtf(var + 1e-5f);
#pragma unroll
    for (int j = 0; j < 3; ++j) {
        int d = t + j * 256;
        float zz = xz[(size_t)row * 1536 + 768 + d];
        float sil = zz * sigmoidf_(zz);
        g[(size_t)row * 768 + d] =
            f2bf(((vals[j] - mean) * rstd * onw[d] + onb[d]) * sil);
    }
}

// ---------------- final: (B*L,384) -> (B,384,32,32) ----------------
__global__ __launch_bounds__(256) void out_tr_k(const float* __restrict__ xh,
                                                float* __restrict__ out) {
    int bc = blockIdx.x;
    int b = bc / 384, ch = bc % 384;
    for (int p = threadIdx.x; p < 1024; p += 256)
        out[(size_t)bc * 1024 + p] = xh[((size_t)(b * 1024 + p)) * 384 + ch];
}

extern "C" void kernel_launch(void* const* d_in, const int* in_sizes, int n_in,
                              void* d_out, int out_size, void* d_ws, size_t ws_size,
                              hipStream_t stream) {
    const float* x    = (const float*)d_in[0];
    const float* skip = (const float*)d_in[1];
    const float* pew  = (const float*)d_in[2];
    const float* pnw  = (const float*)d_in[3];
    const float* pnb  = (const float*)d_in[4];
    const float* lpw  = (const float*)d_in[5];
    const float* lpb  = (const float*)d_in[6];
    const float* blw  = (const float*)d_in[7];
    const float* blb  = (const float*)d_in[8];
    const float* inw  = (const float*)d_in[9];
    const float* cw   = (const float*)d_in[10];
    const float* cb   = (const float*)d_in[11];
    const float* xpw  = (const float*)d_in[12];
    const float* dtw  = (const float*)d_in[13];
    const float* dtbi = (const float*)d_in[14];
    const float* alog = (const float*)d_in[15];
    const float* ds   = (const float*)d_in[16];
    const float* onw  = (const float*)d_in[17];
    const float* onb  = (const float*)d_in[18];
    const float* ow   = (const float*)d_in[19];
    float* out = (float*)d_out;

    char* base = (char*)d_ws;
    auto alloc = [&](size_t bytes) -> char* {
        char* p = base;
        base += (bytes + 255) & ~(size_t)255;
        return p;
    };
    float*  xh   = (float*)alloc(2048 * 384 * 4);
    ushort* hbuf = (ushort*)alloc(2048 * 768 * 2);   // bf16: concat / ln-out / g
    float*  xz   = (float*)alloc((size_t)2048 * 1536 * 4);
    float*  xc   = (float*)alloc(2048 * 768 * 4);
    float*  dbl  = (float*)alloc(8192 * 56 * 4);
    float*  dtb  = (float*)alloc((size_t)8192 * 768 * 4);
    float*  y4   = (float*)alloc((size_t)8192 * 768 * 4);
    float*  Pg   = (float*)alloc((size_t)8 * 16 * 768 * 16 * 4);
    float*  Hg   = (float*)alloc((size_t)8 * 16 * 768 * 16 * 4);
    ushort* xspe = (ushort*)alloc(512 * 768 * 2);
    float*  t1   = (float*)alloc(512 * 1536 * 4);
    ushort* wpe  = (ushort*)alloc((size_t)1536 * 768 * 2);
    ushort* wlp  = (ushort*)alloc(384 * 768 * 2);
    ushort* winb = (ushort*)alloc((size_t)2 * 1536 * 384 * 2);
    ushort* wob  = (ushort*)alloc((size_t)2 * 384 * 768 * 2);

    // ---- weight conversions (bf16) ----
    cvt_k<<<1152, 256, 0, stream>>>(pew, wpe, 1536 * 768 / 4);
    cvt_k<<<288, 256, 0, stream>>>(lpw, wlp, 384 * 768 / 4);
    cvt_k<<<1152, 256, 0, stream>>>(inw, winb, 2 * 1536 * 384 / 4);
    cvt_k<<<576, 256, 0, stream>>>(ow, wob, 2 * 384 * 768 / 4);

    // ---- Stage A: patch-expand + LN + concat skip + linear ----
    transpose_x_k<<<512, 256, 0, stream>>>(x, xspe);
    gemm_bf<<<dim3(12, 4), 256, 0, stream>>>(xspe, wpe, nullptr, nullptr, t1,
                                             512, 1536, 768);
    pe_concat_k<<<2048, 256, 0, stream>>>(t1, skip, pnw, pnb, hbuf);
    gemm_bf<<<dim3(3, 16), 256, 0, stream>>>(hbuf, wlp, lpb, nullptr, xh,
                                             2048, 384, 768);

    // ---- 2 VSS blocks ----
    for (int blk = 0; blk < 2; ++blk) {
        const ushort* inw_i = winb + (size_t)blk * 1536 * 384;
        const float* cw_i  = cw + (size_t)blk * 768 * 9;
        const float* cb_i  = cb + (size_t)blk * 768;
        const float* xpw_i = xpw + (size_t)blk * 4 * 56 * 768;
        const float* dtw_i = dtw + (size_t)blk * 4 * 768 * 24;
        const float* dtb_i = dtbi + (size_t)blk * 4 * 768;
        const float* al_i  = alog + (size_t)blk * 4 * 768 * 16;
        const float* ds_i  = ds + (size_t)blk * 4 * 768;
        const float* onw_i = onw + (size_t)blk * 768;
        const float* onb_i = onb + (size_t)blk * 768;
        const ushort* ow_i = wob + (size_t)blk * 384 * 768;

        ln_rows_384<<<2048, 256, 0, stream>>>(xh, blw + blk * 384, blb + blk * 384,
                                              hbuf);
        gemm_bf<<<dim3(12, 16), 256, 0, stream>>>(hbuf, inw_i, nullptr, nullptr,
                                                  xz, 2048, 1536, 384);
        conv_silu_k<<<2048, 256, 0, stream>>>(xz, cw_i, cb_i, xc);
        xproj_k<<<dim3(256, 4), 64, 0, stream>>>(xc, xpw_i, dbl);
        dtproj_k<<<1024, 256, 0, stream>>>(dbl, dtw_i, dtb_i, dtb);
        scan_p1<<<dim3(12, 15, 8), 64, 0, stream>>>(dtb, dbl, xc, al_i, Pg, Hg);
        scan_p2<<<dim3(12, 16, 8), 64, 0, stream>>>(dtb, dbl, xc, al_i, Pg, Hg, y4);
        fuse_out_k<<<2048, 256, 0, stream>>>(y4, xc, xz, ds_i, onw_i, onb_i, hbuf);
        gemm_bf<<<dim3(3, 16), 256, 0, stream>>>(hbuf, ow_i, nullptr, xh, xh,
                                                 2048, 384, 768);
    }

    out_tr_k<<<768, 256, 0, stream>>>(xh, out);
}

// Round 4
// 589.249 us; speedup vs baseline: 2.1107x; 1.0100x over previous
//
#include <hip/hip_runtime.h>
#include <math.h>

// Problem constants: B=2, H=W=32 (after expand), L=1024, out_dim=384, Di=768,
// K=4 directions, N=16 state, R=24, depth=2. fp32 in/out; bf16 MFMA GEMMs.

typedef __attribute__((ext_vector_type(8))) short s8v;   // 8 bf16 = 4 VGPRs
typedef __attribute__((ext_vector_type(4))) float f4v;

static __device__ __forceinline__ float sigmoidf_(float x) {
    return 1.f / (1.f + __expf(-x));
}
static __device__ __forceinline__ ushort f2bf(float x) {
    unsigned u = __float_as_uint(x);
    return (ushort)((u + 0x7fff + ((u >> 16) & 1)) >> 16);   // RNE
}

// Scan-order <-> spatial-position map. Involution for all k.
static __device__ __forceinline__ int scan_pos(int k, int l) {
    int m = (k & 2) ? (1023 - l) : l;
    return (k & 1) ? (((m & 31) << 5) | (m >> 5)) : m;
}

// ---------------- all weight conversions fp32->bf16 in ONE kernel ----------------
// plain: wpe 294912 f4 | wlp 73728 | winb 294912 | wob 147456  (total 811008 f4)
// wxpp: 2 x 256(n=k*64+c, c<56 valid) x 768, zero-padded        (98304 f4)
// wdtp: 2x4x768 rows x 32 (r<24 valid), zero-padded             (49152 f4)
__global__ __launch_bounds__(256) void cvt_all_k(
    const float* __restrict__ pew, const float* __restrict__ lpw,
    const float* __restrict__ inw, const float* __restrict__ ow,
    const float* __restrict__ xpw, const float* __restrict__ dtw,
    ushort* __restrict__ wpe, ushort* __restrict__ wlp,
    ushort* __restrict__ winb, ushort* __restrict__ wob,
    ushort* __restrict__ wxpp, ushort* __restrict__ wdtp) {
    int g = blockIdx.x * 256 + threadIdx.x;
    if (g < 811008) {
        const float* s; ushort* d; int off;
        if (g < 294912)      { s = pew;  d = wpe;  off = g; }
        else if (g < 368640) { s = lpw;  d = wlp;  off = g - 294912; }
        else if (g < 663552) { s = inw;  d = winb; off = g - 368640; }
        else                 { s = ow;   d = wob;  off = g - 663552; }
        float4 v = ((const float4*)s)[off];
        ushort4 o = {f2bf(v.x), f2bf(v.y), f2bf(v.z), f2bf(v.w)};
        ((ushort4*)d)[off] = o;
    } else if (g < 909312) {
        int e = g - 811008;
        int blkb = e / 49152, rem = e % 49152;
        int n = rem / 192, q = rem % 192;
        int k = n >> 6, c = n & 63;
        ushort4 o = {0, 0, 0, 0};
        if (c < 56) {
            float4 v = *(const float4*)(xpw +
                ((size_t)((blkb * 4 + k) * 56 + c)) * 768 + q * 4);
            o = {f2bf(v.x), f2bf(v.y), f2bf(v.z), f2bf(v.w)};
        }
        ((ushort4*)wxpp)[e] = o;
    } else {
        int e = g - 909312;          // 49152 groups
        int rowk = e >> 3, q = e & 7;
        ushort4 o = {0, 0, 0, 0};
        if (q < 6) {
            float4 v = *(const float4*)(dtw + (size_t)rowk * 24 + q * 4);
            o = {f2bf(v.x), f2bf(v.y), f2bf(v.z), f2bf(v.w)};
        }
        ((ushort4*)wdtp)[e] = o;
    }
}

// ---------------- tiled transpose: x (B,768,256) -> (B*256,768) bf16 -------------
__global__ __launch_bounds__(256) void tr_x_k(const float* __restrict__ x,
                                              ushort* __restrict__ o) {
    __shared__ float tile[32][33];
    int b = blockIdx.z, c0 = blockIdx.y * 32, s0 = blockIdx.x * 32;
    int tx = threadIdx.x & 31, ty = threadIdx.x >> 5;
    for (int i = ty; i < 32; i += 8)
        tile[i][tx] = x[((size_t)(b * 768 + c0 + i)) * 256 + s0 + tx];
    __syncthreads();
    for (int i = ty; i < 32; i += 8)
        o[((size_t)(b * 256 + s0 + i)) * 768 + c0 + tx] = f2bf(tile[tx][i]);
}

// ---------------- tiled transpose: skip (B,384,1024) -> cin cols [384,768) bf16 --
__global__ __launch_bounds__(256) void tr_skip_k(const float* __restrict__ skip,
                                                 ushort* __restrict__ cin) {
    __shared__ float tile[32][33];
    int b = blockIdx.z, c0 = blockIdx.y * 32, s0 = blockIdx.x * 32;
    int tx = threadIdx.x & 31, ty = threadIdx.x >> 5;
    for (int i = ty; i < 32; i += 8)
        tile[i][tx] = skip[((size_t)(b * 384 + c0 + i)) * 1024 + s0 + tx];
    __syncthreads();
    for (int i = ty; i < 32; i += 8)
        cin[((size_t)(b * 1024 + s0 + i)) * 768 + 384 + c0 + tx] = f2bf(tile[tx][i]);
}

// ---------------- tiled transpose: xh (B*1024,384) -> out (B,384,1024) fp32 ------
__global__ __launch_bounds__(256) void tr_out_k(const float* __restrict__ xh,
                                                float* __restrict__ out) {
    __shared__ float tile[32][33];
    int b = blockIdx.z, p0 = blockIdx.x * 32, c0 = blockIdx.y * 32;
    int tx = threadIdx.x & 31, ty = threadIdx.x >> 5;
    for (int i = ty; i < 32; i += 8)
        tile[i][tx] = xh[((size_t)(b * 1024 + p0 + i)) * 384 + c0 + tx];
    __syncthreads();
    for (int i = ty; i < 32; i += 8)
        out[((size_t)(b * 384 + c0 + i)) * 1024 + p0 + tx] = tile[tx][i];
}

// ---------------- bf16 NT MFMA GEMM, z-batched, 2 epilogue modes -----------------
// C[m,n] = sum_k A[m,k]*B[n,k]; mode 0: +bias? +res?; mode 1: softplus(acc+bias).
// M%128==0, N%128==0, K%32==0. Block 256 = 4 waves (2x2), wave = 64x64.
__global__ __launch_bounds__(256) void gemm_bf(const ushort* __restrict__ A,
                                               const ushort* __restrict__ B,
                                               const float* __restrict__ bias,
                                               const float* __restrict__ res,
                                               float* __restrict__ C,
                                               int M, int N, int K,
                                               long sAz, long sBz, long sBiz,
                                               long sCz, int mode) {
    __shared__ ushort Als[128][40];   // row = 80 B (16B-aligned), 20-bank stride
    __shared__ ushort Bls[128][40];
    A += (size_t)blockIdx.z * sAz;
    B += (size_t)blockIdx.z * sBz;
    C += (size_t)blockIdx.z * sCz;
    if (bias) bias += (size_t)blockIdx.z * sBiz;
    int t = threadIdx.x;
    int bm = blockIdx.y * 128, bn = blockIdx.x * 128;
    int lane = t & 63, w = t >> 6;
    int wm = (w & 1) * 64, wn = (w >> 1) * 64;
    int r16 = lane & 15, quad = lane >> 4;
    int srow = t >> 1, shalf = t & 1;
    f4v acc[4][4] = {};
    const ushort* Ag = A + (size_t)(bm + srow) * K + shalf * 16;
    const ushort* Bg = B + (size_t)(bn + srow) * K + shalf * 16;
    for (int k0 = 0; k0 < K; k0 += 32) {
        uint4 a0 = *(const uint4*)(Ag + k0);
        uint4 a1 = *(const uint4*)(Ag + k0 + 8);
        uint4 b0 = *(const uint4*)(Bg + k0);
        uint4 b1 = *(const uint4*)(Bg + k0 + 8);
        __syncthreads();
        *(uint4*)&Als[srow][shalf * 16] = a0;
        *(uint4*)&Als[srow][shalf * 16 + 8] = a1;
        *(uint4*)&Bls[srow][shalf * 16] = b0;
        *(uint4*)&Bls[srow][shalf * 16 + 8] = b1;
        __syncthreads();
        s8v af[4], bfr[4];
#pragma unroll
        for (int i = 0; i < 4; ++i) {
            af[i]  = *(const s8v*)&Als[wm + i * 16 + r16][quad * 8];
            bfr[i] = *(const s8v*)&Bls[wn + i * 16 + r16][quad * 8];
        }
#pragma unroll
        for (int i = 0; i < 4; ++i)
#pragma unroll
            for (int j = 0; j < 4; ++j)
                acc[i][j] = __builtin_amdgcn_mfma_f32_16x16x32_bf16(
                    af[i], bfr[j], acc[i][j], 0, 0, 0);
    }
    // D mapping: col=lane&15, row=quad*4+reg (m89-verified)
#pragma unroll
    for (int i = 0; i < 4; ++i) {
        int row0 = bm + wm + i * 16 + quad * 4;
#pragma unroll
        for (int j = 0; j < 4; ++j) {
            int col = bn + wn + j * 16 + r16;
            float bv = bias ? bias[col] : 0.f;
#pragma unroll
            for (int r = 0; r < 4; ++r) {
                int row = row0 + r;
                float v = acc[i][j][r] + bv;
                if (mode == 1) {
                    v = (v > 20.f) ? v : log1pf(__expf(v));
                } else if (res) {
                    v += res[(size_t)row * N + col];
                }
                C[(size_t)row * N + col] = v;
            }
        }
    }
}

// ---------------- pixel-shuffle + LN -> cin cols [0,384) bf16 (wave/row) ---------
__global__ __launch_bounds__(256) void pe_ln_k(const float* __restrict__ t1,
                                               const float* __restrict__ pnw,
                                               const float* __restrict__ pnb,
                                               ushort* __restrict__ cin) {
    int w = threadIdx.x >> 6, lane = threadIdx.x & 63;
    int row = blockIdx.x * 4 + w;      // (b*1024 + p), grid 512
    int b = row >> 10, p = row & 1023;
    int r = p >> 5, col = p & 31;
    int i = r >> 1, a = r & 1, j = col >> 1, b2 = col & 1;
    const float* src = t1 + ((size_t)(b * 256 + i * 16 + j)) * 1536 + (a * 2 + b2) * 384;
    float v[6], s1 = 0.f, s2 = 0.f;
#pragma unroll
    for (int q = 0; q < 6; ++q) {
        v[q] = src[lane + 64 * q];
        s1 += v[q]; s2 += v[q] * v[q];
    }
#pragma unroll
    for (int m = 1; m < 64; m <<= 1) {
        s1 += __shfl_xor(s1, m); s2 += __shfl_xor(s2, m);
    }
    float mean = s1 * (1.f / 384.f);
    float rstd = rsqrtf(s2 * (1.f / 384.f) - mean * mean + 1e-5f);
    ushort* o = cin + (size_t)row * 768;
#pragma unroll
    for (int q = 0; q < 6; ++q) {
        int c = lane + 64 * q;
        o[c] = f2bf((v[q] - mean) * rstd * pnw[c] + pnb[c]);
    }
}

// ---------------- row LayerNorm over 384 cols -> bf16 (wave/row) ----------------
__global__ __launch_bounds__(256) void ln_rows_384(const float* __restrict__ in,
                                                   const float* __restrict__ wgt,
                                                   const float* __restrict__ bb,
                                                   ushort* __restrict__ out) {
    int w = threadIdx.x >> 6, lane = threadIdx.x & 63;
    int row = blockIdx.x * 4 + w;      // grid 512
    const float* x = in + (size_t)row * 384;
    float v[6], s1 = 0.f, s2 = 0.f;
#pragma unroll
    for (int q = 0; q < 6; ++q) {
        v[q] = x[lane + 64 * q];
        s1 += v[q]; s2 += v[q] * v[q];
    }
#pragma unroll
    for (int m = 1; m < 64; m <<= 1) {
        s1 += __shfl_xor(s1, m); s2 += __shfl_xor(s2, m);
    }
    float mean = s1 * (1.f / 384.f);
    float rstd = rsqrtf(s2 * (1.f / 384.f) - mean * mean + 1e-5f);
#pragma unroll
    for (int q = 0; q < 6; ++q) {
        int c = lane + 64 * q;
        out[(size_t)row * 384 + c] = f2bf((v[q] - mean) * rstd * wgt[c] + bb[c]);
    }
}

// ---------------- depthwise 3x3 conv + bias + SiLU -> xc fp32 + xcb bf16 ---------
__global__ __launch_bounds__(256) void conv_silu_k(const float* __restrict__ xz,
                                                   const float* __restrict__ cw,
                                                   const float* __restrict__ cb,
                                                   float* __restrict__ xc,
                                                   ushort* __restrict__ xcb) {
    int row = blockIdx.x;
    int b = row >> 10, p = row & 1023;
    int r = p >> 5, col = p & 31;
    for (int d = threadIdx.x; d < 768; d += 256) {
        float acc = cb[d];
#pragma unroll
        for (int dy = 0; dy < 3; ++dy) {
            int rr = r + dy - 1;
            if ((unsigned)rr > 31u) continue;
#pragma unroll
            for (int dx = 0; dx < 3; ++dx) {
                int cc = col + dx - 1;
                if ((unsigned)cc > 31u) continue;
                acc += cw[d * 9 + dy * 3 + dx] *
                       xz[((size_t)(b * 1024 + rr * 32 + cc)) * 1536 + d];
            }
        }
        float o = acc * sigmoidf_(acc);
        xc[(size_t)row * 768 + d] = o;
        xcb[(size_t)row * 768 + d] = f2bf(o);
    }
}

// ---------------- prep: scatter B/C to scan order; extract dtr (bf16) ------------
// dblp: (2048, 256) spatial, cols n=k*64+{0..24 dtr, 24..40 B, 40..56 C}.
// y==0: dblBC[kb][l][32] fp32 (B|C).  y==1: dtrb[k][m][32] bf16, r>=24 -> 0.
__global__ __launch_bounds__(256) void prep_k(const float* __restrict__ dblp,
                                              float* __restrict__ dblBC,
                                              ushort* __restrict__ dtrb) {
    int e = blockIdx.x * 256 + threadIdx.x;
    if (blockIdx.y == 0) {
        int j = e & 31, l = (e >> 5) & 1023, kb = e >> 15;
        int k = kb & 3, b = kb >> 2;
        int p = scan_pos(k, l);
        dblBC[e] = dblp[((size_t)(b * 1024 + p)) * 256 + k * 64 + 24 + j];
    } else {
        int r = e & 31, m = (e >> 5) & 2047, k = e >> 16;
        float v = (r < 24) ? dblp[(size_t)m * 256 + k * 64 + r] : 0.f;
        dtrb[e] = f2bf(v);
    }
}

// ======== selective scan, affine-chunked over L (2 kernels, no shuffles) ========
// dt_sp layout [k][b*1024+p][768] (spatial rows); dblBC scan-order.

__global__ __launch_bounds__(64) void scan_p1(const float* __restrict__ dt_sp,
                                              const float* __restrict__ dblBC,
                                              const float* __restrict__ xc,
                                              const float* __restrict__ alog,
                                              float* __restrict__ Pg,
                                              float* __restrict__ Hg) {
    __shared__ float sB[32][16];
    int lane = threadIdx.x;
    int d0 = blockIdx.x * 64, ch = blockIdx.y, kb = blockIdx.z;
    int k = kb & 3, b = kb >> 2;
    int d = d0 + lane;
    float A2[16];
    {
        const float4* ap = (const float4*)(alog + ((size_t)(k * 768 + d)) * 16);
#pragma unroll
        for (int q = 0; q < 4; ++q) {
            float4 v = ap[q];
            A2[4 * q + 0] = -__expf(v.x) * 1.44269504f;
            A2[4 * q + 1] = -__expf(v.y) * 1.44269504f;
            A2[4 * q + 2] = -__expf(v.z) * 1.44269504f;
            A2[4 * q + 3] = -__expf(v.w) * 1.44269504f;
        }
    }
    const float* dts = dt_sp + ((size_t)(k * 2048 + b * 1024)) * 768 + d;
    const float* bcp = dblBC + (size_t)kb * 1024 * 32;
    const float* xp  = xc + (size_t)b * 786432 + d0;
    int l0 = ch * 64;
    float h[16], P[16];
#pragma unroll
    for (int n = 0; n < 16; ++n) { h[n] = 0.f; P[n] = 1.f; }
    int bi = lane >> 4, bn_ = lane & 15;
#pragma unroll 1
    for (int w = 0; w < 2; ++w) {
        int lw = l0 + w * 32;
        float rdt[32], ru[32], rB[8];
#pragma unroll
        for (int i = 0; i < 32; ++i) {
            int p = scan_pos(k, lw + i);
            rdt[i] = dts[(size_t)p * 768];
            ru[i] = xp[(size_t)p * 768 + lane];
        }
#pragma unroll
        for (int j = 0; j < 8; ++j)
            rB[j] = bcp[(size_t)(lw + bi + 4 * j) * 32 + bn_];
        __syncthreads();
#pragma unroll
        for (int j = 0; j < 8; ++j) sB[bi + 4 * j][bn_] = rB[j];
        __syncthreads();
#pragma unroll 4
        for (int i = 0; i < 32; ++i) {
            float dtv = rdt[i], dtu = dtv * ru[i];
            const float4* B4 = (const float4*)&sB[i][0];
            float4 q0 = B4[0], q1 = B4[1], q2 = B4[2], q3 = B4[3];
            float Bv[16] = {q0.x, q0.y, q0.z, q0.w, q1.x, q1.y, q1.z, q1.w,
                            q2.x, q2.y, q2.z, q2.w, q3.x, q3.y, q3.z, q3.w};
#pragma unroll
            for (int n = 0; n < 16; ++n) {
                float a = __builtin_amdgcn_exp2f(dtv * A2[n]);
                P[n] *= a;
                h[n] = a * h[n] + dtu * Bv[n];
            }
        }
    }
    float* pp = Pg + (((size_t)kb * 16 + ch) * 768 + d) * 16;
    float* hp = Hg + (((size_t)kb * 16 + ch) * 768 + d) * 16;
#pragma unroll
    for (int q = 0; q < 4; ++q) {
        float4 pv = {P[4 * q], P[4 * q + 1], P[4 * q + 2], P[4 * q + 3]};
        float4 hv = {h[4 * q], h[4 * q + 1], h[4 * q + 2], h[4 * q + 3]};
        *(float4*)(pp + 4 * q) = pv;
        *(float4*)(hp + 4 * q) = hv;
    }
}

__global__ __launch_bounds__(64) void scan_p2(const float* __restrict__ dt_sp,
                                              const float* __restrict__ dblBC,
                                              const float* __restrict__ xc,
                                              const float* __restrict__ alog,
                                              const float* __restrict__ Pg,
                                              const float* __restrict__ Hg,
                                              float* __restrict__ y4) {
    __shared__ float sB[32][16];
    __shared__ float sC[32][16];
    int lane = threadIdx.x;
    int d0 = blockIdx.x * 64, ch = blockIdx.y, kb = blockIdx.z;
    int k = kb & 3, b = kb >> 2;
    int d = d0 + lane;
    float A2[16];
    {
        const float4* ap = (const float4*)(alog + ((size_t)(k * 768 + d)) * 16);
#pragma unroll
        for (int q = 0; q < 4; ++q) {
            float4 v = ap[q];
            A2[4 * q + 0] = -__expf(v.x) * 1.44269504f;
            A2[4 * q + 1] = -__expf(v.y) * 1.44269504f;
            A2[4 * q + 2] = -__expf(v.z) * 1.44269504f;
            A2[4 * q + 3] = -__expf(v.w) * 1.44269504f;
        }
    }
    float h[16];
#pragma unroll
    for (int n = 0; n < 16; ++n) h[n] = 0.f;
    for (int j = 0; j < ch; ++j) {
        const float4* pj = (const float4*)(Pg + (((size_t)kb * 16 + j) * 768 + d) * 16);
        const float4* hj = (const float4*)(Hg + (((size_t)kb * 16 + j) * 768 + d) * 16);
#pragma unroll
        for (int q = 0; q < 4; ++q) {
            float4 pv = pj[q], hv = hj[q];
            h[4 * q + 0] = pv.x * h[4 * q + 0] + hv.x;
            h[4 * q + 1] = pv.y * h[4 * q + 1] + hv.y;
            h[4 * q + 2] = pv.z * h[4 * q + 2] + hv.z;
            h[4 * q + 3] = pv.w * h[4 * q + 3] + hv.w;
        }
    }
    const float* dts = dt_sp + ((size_t)(k * 2048 + b * 1024)) * 768 + d;
    const float* bcp = dblBC + (size_t)kb * 1024 * 32;
    const float* xp  = xc + (size_t)b * 786432 + d0;
    float* yp = y4 + (size_t)kb * 786432 + d;
    int l0 = ch * 64;
    int bi = lane >> 4, bn_ = lane & 15;
#pragma unroll 1
    for (int w = 0; w < 2; ++w) {
        int lw = l0 + w * 32;
        float rdt[32], ru[32], rB[8], rC[8];
#pragma unroll
        for (int i = 0; i < 32; ++i) {
            int p = scan_pos(k, lw + i);
            rdt[i] = dts[(size_t)p * 768];
            ru[i] = xp[(size_t)p * 768 + lane];
        }
#pragma unroll
        for (int j = 0; j < 8; ++j) {
            rB[j] = bcp[(size_t)(lw + bi + 4 * j) * 32 + bn_];
            rC[j] = bcp[(size_t)(lw + bi + 4 * j) * 32 + 16 + bn_];
        }
        __syncthreads();
#pragma unroll
        for (int j = 0; j < 8; ++j) {
            sB[bi + 4 * j][bn_] = rB[j];
            sC[bi + 4 * j][bn_] = rC[j];
        }
        __syncthreads();
#pragma unroll 4
        for (int i = 0; i < 32; ++i) {
            float dtv = rdt[i], dtu = dtv * ru[i];
            const float4* B4 = (const float4*)&sB[i][0];
            const float4* C4 = (const float4*)&sC[i][0];
            float4 q0 = B4[0], q1 = B4[1], q2 = B4[2], q3 = B4[3];
            float Bv[16] = {q0.x, q0.y, q0.z, q0.w, q1.x, q1.y, q1.z, q1.w,
                            q2.x, q2.y, q2.z, q2.w, q3.x, q3.y, q3.z, q3.w};
            float4 c0 = C4[0], c1 = C4[1], c2 = C4[2], c3 = C4[3];
            float Cv[16] = {c0.x, c0.y, c0.z, c0.w, c1.x, c1.y, c1.z, c1.w,
                            c2.x, c2.y, c2.z, c2.w, c3.x, c3.y, c3.z, c3.w};
            float y = 0.f;
#pragma unroll
            for (int n = 0; n < 16; ++n) {
                float a = __builtin_amdgcn_exp2f(dtv * A2[n]);
                h[n] = a * h[n] + dtu * Bv[n];
                y += h[n] * Cv[n];
            }
            int p = scan_pos(k, lw + i);
            yp[(size_t)p * 768] = y;
        }
    }
}

// ---------------- sum 4 dirs + D*u, out-LN, * silu(z) -> g bf16 (wave/row) -------
__global__ __launch_bounds__(256) void fuse_out_k(const float* __restrict__ y4,
                                                  const float* __restrict__ xc,
                                                  const float* __restrict__ xz,
                                                  const float* __restrict__ ds,
                                                  const float* __restrict__ onw,
                                                  const float* __restrict__ onb,
                                                  ushort* __restrict__ g) {
    int w = threadIdx.x >> 6, lane = threadIdx.x & 63;
    int row = blockIdx.x * 4 + w;      // grid 512
    int b = row >> 10, p = row & 1023;
    float v[12], s1 = 0.f, s2 = 0.f;
#pragma unroll
    for (int q = 0; q < 12; ++q) {
        int d = lane + 64 * q;
        float u = xc[(size_t)row * 768 + d];
        float dsum = ds[d] + ds[768 + d] + ds[1536 + d] + ds[2304 + d];
        float val = dsum * u;
#pragma unroll
        for (int k = 0; k < 4; ++k)
            val += y4[(((size_t)(b * 4 + k)) * 1024 + p) * 768 + d];
        v[q] = val; s1 += val; s2 += val * val;
    }
#pragma unroll
    for (int m = 1; m < 64; m <<= 1) {
        s1 += __shfl_xor(s1, m); s2 += __shfl_xor(s2, m);
    }
    float mean = s1 * (1.f / 768.f);
    float rstd = rsqrtf(s2 * (1.f / 768.f) - mean * mean + 1e-5f);
#pragma unroll
    for (int q = 0; q < 12; ++q) {
        int d = lane + 64 * q;
        float zz = xz[(size_t)row * 1536 + 768 + d];
        float sil = zz * sigmoidf_(zz);
        g[(size_t)row * 768 + d] = f2bf(((v[q] - mean) * rstd * onw[d] + onb[d]) * sil);
    }
}

extern "C" void kernel_launch(void* const* d_in, const int* in_sizes, int n_in,
                              void* d_out, int out_size, void* d_ws, size_t ws_size,
                              hipStream_t stream) {
    const float* x    = (const float*)d_in[0];
    const float* skip = (const float*)d_in[1];
    const float* pew  = (const float*)d_in[2];
    const float* pnw  = (const float*)d_in[3];
    const float* pnb  = (const float*)d_in[4];
    const float* lpw  = (const float*)d_in[5];
    const float* lpb  = (const float*)d_in[6];
    const float* blw  = (const float*)d_in[7];
    const float* blb  = (const float*)d_in[8];
    const float* inw  = (const float*)d_in[9];
    const float* cw   = (const float*)d_in[10];
    const float* cb   = (const float*)d_in[11];
    const float* xpw  = (const float*)d_in[12];
    const float* dtw  = (const float*)d_in[13];
    const float* dtbi = (const float*)d_in[14];
    const float* alog = (const float*)d_in[15];
    const float* ds   = (const float*)d_in[16];
    const float* onw  = (const float*)d_in[17];
    const float* onb  = (const float*)d_in[18];
    const float* ow   = (const float*)d_in[19];
    float* out = (float*)d_out;

    char* base = (char*)d_ws;
    auto alloc = [&](size_t bytes) -> char* {
        char* p = base;
        base += (bytes + 255) & ~(size_t)255;
        return p;
    };
    float*  xh    = (float*)alloc(2048 * 384 * 4);
    ushort* hbuf  = (ushort*)alloc(2048 * 768 * 2);
    float*  xz    = (float*)alloc((size_t)2048 * 1536 * 4);
    float*  xc    = (float*)alloc(2048 * 768 * 4);
    ushort* xcb   = (ushort*)alloc(2048 * 768 * 2);
    float*  dblp  = (float*)alloc(2048 * 256 * 4);
    float*  dblBC = (float*)alloc(8192 * 32 * 4);
    ushort* dtrb  = (ushort*)alloc((size_t)4 * 2048 * 32 * 2);
    float*  dtsp  = (float*)alloc((size_t)4 * 2048 * 768 * 4);
    float*  y4    = (float*)alloc((size_t)8192 * 768 * 4);
    float*  Pg    = (float*)alloc((size_t)8 * 16 * 768 * 16 * 4);
    float*  Hg    = (float*)alloc((size_t)8 * 16 * 768 * 16 * 4);
    ushort* xspe  = (ushort*)alloc(512 * 768 * 2);
    float*  t1    = (float*)alloc(512 * 1536 * 4);
    ushort* wpe   = (ushort*)alloc((size_t)1536 * 768 * 2);
    ushort* wlp   = (ushort*)alloc(384 * 768 * 2);
    ushort* winb  = (ushort*)alloc((size_t)2 * 1536 * 384 * 2);
    ushort* wob   = (ushort*)alloc((size_t)2 * 384 * 768 * 2);
    ushort* wxpp  = (ushort*)alloc((size_t)2 * 256 * 768 * 2);
    ushort* wdtp  = (ushort*)alloc((size_t)2 * 4 * 768 * 32 * 2);

    cvt_all_k<<<3744, 256, 0, stream>>>(pew, lpw, inw, ow, xpw, dtw,
                                        wpe, wlp, winb, wob, wxpp, wdtp);

    // ---- Stage A ----
    tr_x_k<<<dim3(8, 24, 2), 256, 0, stream>>>(x, xspe);
    gemm_bf<<<dim3(12, 4), 256, 0, stream>>>(xspe, wpe, nullptr, nullptr, t1,
                                             512, 1536, 768, 0, 0, 0, 0, 0);
    pe_ln_k<<<512, 256, 0, stream>>>(t1, pnw, pnb, hbuf);
    tr_skip_k<<<dim3(32, 12, 2), 256, 0, stream>>>(skip, hbuf);
    gemm_bf<<<dim3(3, 16), 256, 0, stream>>>(hbuf, wlp, lpb, nullptr, xh,
                                             2048, 384, 768, 0, 0, 0, 0, 0);

    // ---- 2 VSS blocks ----
    for (int blk = 0; blk < 2; ++blk) {
        const ushort* inw_i = winb + (size_t)blk * 1536 * 384;
        const float*  cw_i  = cw + (size_t)blk * 768 * 9;
        const float*  cb_i  = cb + (size_t)blk * 768;
        const ushort* xpw_i = wxpp + (size_t)blk * 256 * 768;
        const ushort* dtw_i = wdtp + (size_t)blk * 4 * 768 * 32;
        const float*  dtb_i = dtbi + (size_t)blk * 4 * 768;
        const float*  al_i  = alog + (size_t)blk * 4 * 768 * 16;
        const float*  ds_i  = ds + (size_t)blk * 4 * 768;
        const float*  onw_i = onw + (size_t)blk * 768;
        const float*  onb_i = onb + (size_t)blk * 768;
        const ushort* ow_i  = wob + (size_t)blk * 384 * 768;

        ln_rows_384<<<512, 256, 0, stream>>>(xh, blw + blk * 384, blb + blk * 384,
                                             hbuf);
        gemm_bf<<<dim3(12, 16), 256, 0, stream>>>(hbuf, inw_i, nullptr, nullptr,
                                                  xz, 2048, 1536, 384,
                                                  0, 0, 0, 0, 0);
        conv_silu_k<<<2048, 256, 0, stream>>>(xz, cw_i, cb_i, xc, xcb);
        gemm_bf<<<dim3(2, 16), 256, 0, stream>>>(xcb, xpw_i, nullptr, nullptr,
                                                 dblp, 2048, 256, 768,
                                                 0, 0, 0, 0, 0);
        prep_k<<<dim3(1024, 2), 256, 0, stream>>>(dblp, dblBC, dtrb);
        gemm_bf<<<dim3(6, 16, 4), 256, 0, stream>>>(dtrb, dtw_i, dtb_i, nullptr,
                                                    dtsp, 2048, 768, 32,
                                                    2048 * 32, 768 * 32, 768,
                                                    (long)2048 * 768, 1);
        scan_p1<<<dim3(12, 15, 8), 64, 0, stream>>>(dtsp, dblBC, xc, al_i, Pg, Hg);
        scan_p2<<<dim3(12, 16, 8), 64, 0, stream>>>(dtsp, dblBC, xc, al_i, Pg, Hg,
                                                    y4);
        fuse_out_k<<<512, 256, 0, stream>>>(y4, xc, xz, ds_i, onw_i, onb_i, hbuf);
        gemm_bf<<<dim3(3, 16), 256, 0, stream>>>(hbuf, ow_i, nullptr, xh, xh,
                                                 2048, 384, 768, 0, 0, 0, 0, 0);
    }

    tr_out_k<<<dim3(32, 12, 2), 256, 0, stream>>>(xh, out);
}